// Round 1
// baseline (794.431 us; speedup 1.0000x reference)
//
#include <hip/hip_runtime.h>
#include <hip/hip_bf16.h>

#define D_MODEL 1024
#define D_STATE 16
#define DT_RANK 64
#define SEQ 2048
#define BATCH 2
#define M_TOTAL (BATCH * SEQ) /* 4096 rows */
#define P_DIM 96              /* DT_RANK + 2*D_STATE */

typedef __bf16 bf16x8 __attribute__((ext_vector_type(8)));
typedef float f32x4 __attribute__((ext_vector_type(4)));

__device__ __forceinline__ unsigned short f2bf(float f) {
    union { float f; unsigned int u; } v; v.f = f;
    unsigned int r = v.u + 0x7FFFu + ((v.u >> 16) & 1u);
    return (unsigned short)(r >> 16);
}

// ---------- K0: Aneg = -exp(A_log), (1024,16) ----------
__global__ void k_aneg(const float* __restrict__ alog, float* __restrict__ aneg) {
    int i = blockIdx.x * 256 + threadIdx.x;
    if (i < D_MODEL * D_STATE) aneg[i] = -expf(alog[i]);
}

// ---------- K1: x fp32 -> bf16 ----------
__global__ void k_convert_x(const float* __restrict__ x, unsigned short* __restrict__ xb, int n4) {
    int i = blockIdx.x * 256 + threadIdx.x;
    if (i >= n4) return;
    float4 v = reinterpret_cast<const float4*>(x)[i];
    ushort4 o;
    o.x = f2bf(v.x); o.y = f2bf(v.y); o.z = f2bf(v.z); o.w = f2bf(v.w);
    reinterpret_cast<ushort4*>(xb)[i] = o;
}

// ---------- K2: w_in (1024x1024) fp32 -> w_t bf16 transposed [n][k] ----------
__global__ void k_transpose_w(const float* __restrict__ w, unsigned short* __restrict__ wt) {
    __shared__ float tile[32][33];
    int tx = threadIdx.x, ty = threadIdx.y;
    int bx = blockIdx.x, by = blockIdx.y;
    int xc = bx * 32 + tx;
#pragma unroll
    for (int j = 0; j < 4; j++)
        tile[ty + 8 * j][tx] = w[(by * 32 + ty + 8 * j) * D_MODEL + xc];
    __syncthreads();
    int x2 = by * 32 + tx;
#pragma unroll
    for (int j = 0; j < 4; j++)
        wt[(bx * 32 + ty + 8 * j) * D_MODEL + x2] = f2bf(tile[tx][ty + 8 * j]);
}

// ---------- K3: x_in = x @ w_in via bf16 MFMA; per-wave 16x64 tile ----------
__global__ void __launch_bounds__(256) k_gemm1(const unsigned short* __restrict__ xb,
                                               const unsigned short* __restrict__ wt,
                                               float* __restrict__ xin) {
    int wid = blockIdx.x * 4 + (threadIdx.x >> 6);
    int lane = threadIdx.x & 63;
    int m0 = (wid & 255) * 16;  // M/16 = 256 tiles, fastest
    int n0 = (wid >> 8) * 64;   // N/64 = 16 groups
    int c = lane & 15, q = lane >> 4;
    f32x4 acc[4] = {};
    const unsigned short* pa = xb + (m0 + c) * D_MODEL + q * 8;
    const unsigned short* pb = wt + (n0 + c) * D_MODEL + q * 8;
    for (int k0 = 0; k0 < D_MODEL; k0 += 32) {
        bf16x8 a = *reinterpret_cast<const bf16x8*>(pa + k0);
#pragma unroll
        for (int t = 0; t < 4; t++) {
            bf16x8 b = *reinterpret_cast<const bf16x8*>(pb + t * 16 * D_MODEL + k0);
            acc[t] = __builtin_amdgcn_mfma_f32_16x16x32_bf16(a, b, acc[t], 0, 0, 0);
        }
    }
    // C/D layout: col = lane&15, row = (lane>>4)*4 + reg   [verified m89/m91]
#pragma unroll
    for (int t = 0; t < 4; t++)
#pragma unroll
        for (int r = 0; r < 4; r++)
            xin[(m0 + q * 4 + r) * D_MODEL + n0 + t * 16 + c] = acc[t][r];
}

// ---------- K4: proj = x_in @ w_x, (4096 x 96); 4 rows per block ----------
__global__ void __launch_bounds__(128) k_proj(const float* __restrict__ xin,
                                              const float* __restrict__ wx,
                                              float* __restrict__ proj) {
    __shared__ float xrow[4][D_MODEL];
    int m0 = blockIdx.x * 4;
    int tid = threadIdx.x;
#pragma unroll
    for (int rr = 0; rr < 4; rr++)
        for (int i = tid; i < D_MODEL; i += 128)
            xrow[rr][i] = xin[(m0 + rr) * D_MODEL + i];
    __syncthreads();
    if (tid < P_DIM) {
        float a0 = 0.f, a1 = 0.f, a2 = 0.f, a3 = 0.f;
        for (int k = 0; k < D_MODEL; k++) {
            float w = wx[k * P_DIM + tid];
            a0 = fmaf(xrow[0][k], w, a0);
            a1 = fmaf(xrow[1][k], w, a1);
            a2 = fmaf(xrow[2][k], w, a2);
            a3 = fmaf(xrow[3][k], w, a3);
        }
        proj[(m0 + 0) * P_DIM + tid] = a0;
        proj[(m0 + 1) * P_DIM + tid] = a1;
        proj[(m0 + 2) * P_DIM + tid] = a2;
        proj[(m0 + 3) * P_DIM + tid] = a3;
    }
}

// ---------- K5: dt = softplus(dt_low @ w_dt + b_dt)*0.099 + 0.001 ----------
__global__ void __launch_bounds__(256) k_dt(const float* __restrict__ proj,
                                            const float* __restrict__ wdt,
                                            const float* __restrict__ bdt,
                                            float* __restrict__ dt) {
    __shared__ float low[DT_RANK];
    int m = blockIdx.x, tid = threadIdx.x;
    if (tid < DT_RANK) low[tid] = proj[m * P_DIM + tid];
    __syncthreads();
    float acc[4] = {0.f, 0.f, 0.f, 0.f};
    for (int r = 0; r < DT_RANK; r++) {
        float v = low[r];
#pragma unroll
        for (int i = 0; i < 4; i++)
            acc[i] = fmaf(v, wdt[r * D_MODEL + tid + i * 256], acc[i]);
    }
#pragma unroll
    for (int i = 0; i < 4; i++) {
        int d = tid + i * 256;
        float xv = acc[i] + bdt[d];
        float sp = fmaxf(xv, 0.f) + log1pf(expf(-fabsf(xv)));
        dt[m * D_MODEL + d] = sp * 0.099f + 0.001f;
    }
}

// ---------- K6: winp[m,n] = B[m,n] * sum_d dt[m,d]*u[m,d]*Aneg[d,n] ----------
__global__ void __launch_bounds__(256) k_winp(const float* __restrict__ dt,
                                              const float* __restrict__ xin,
                                              const float* __restrict__ aneg,
                                              const float* __restrict__ proj,
                                              float* __restrict__ winp) {
    __shared__ float red[256][17];
    int m = blockIdx.x, tid = threadIdx.x;
    float part[16];
#pragma unroll
    for (int n = 0; n < 16; n++) part[n] = 0.f;
    for (int d = tid; d < D_MODEL; d += 256) {
        float g = dt[m * D_MODEL + d] * xin[m * D_MODEL + d];
        const float4* ar = reinterpret_cast<const float4*>(aneg + d * 16);
#pragma unroll
        for (int j = 0; j < 4; j++) {
            float4 a4 = ar[j];
            part[4 * j + 0] = fmaf(g, a4.x, part[4 * j + 0]);
            part[4 * j + 1] = fmaf(g, a4.y, part[4 * j + 1]);
            part[4 * j + 2] = fmaf(g, a4.z, part[4 * j + 2]);
            part[4 * j + 3] = fmaf(g, a4.w, part[4 * j + 3]);
        }
    }
#pragma unroll
    for (int n = 0; n < 16; n++) red[tid][n] = part[n];
    __syncthreads();
    for (int s = 128; s > 0; s >>= 1) {
        if (tid < s) {
#pragma unroll
            for (int n = 0; n < 16; n++) red[tid][n] += red[tid + s][n];
        }
        __syncthreads();
    }
    if (tid < 16) winp[m * 16 + tid] = proj[m * P_DIM + DT_RANK + tid] * red[0][tid];
}

// ---------- K7: sequential scan; thread = (b,d); LDS-staged 16-step tiles ----------
__global__ void __launch_bounds__(256) k_scan(const float* __restrict__ dt,
                                              const float* __restrict__ xin,
                                              const float* __restrict__ winp,
                                              const float* __restrict__ proj,
                                              const float* __restrict__ aneg,
                                              const float* __restrict__ dp,
                                              float* __restrict__ out) {
    __shared__ float s_dt[16][256], s_u[16][256], s_w[16][16], s_c[16][16];
    int b = blockIdx.x >> 2, dc = blockIdx.x & 3;
    int tid = threadIdx.x;
    int d = dc * 256 + tid;
    float Ad[16];
    const float4* ar = reinterpret_cast<const float4*>(aneg + d * 16);
#pragma unroll
    for (int j = 0; j < 4; j++) {
        float4 a4 = ar[j];
        Ad[4 * j + 0] = a4.x; Ad[4 * j + 1] = a4.y;
        Ad[4 * j + 2] = a4.z; Ad[4 * j + 3] = a4.w;
    }
    float Dpd = dp[d];
    float h[16];
#pragma unroll
    for (int n = 0; n < 16; n++) h[n] = 0.f;

    for (int t0 = 0; t0 < SEQ; t0 += 16) {
        __syncthreads();
#pragma unroll
        for (int r = 0; r < 16; r++) {
            int row = b * SEQ + t0 + r;
            s_dt[r][tid] = dt[row * D_MODEL + d];
            s_u[r][tid] = xin[row * D_MODEL + d];
        }
        {
            int r = tid >> 4, n = tid & 15;
            int row = b * SEQ + t0 + r;
            s_w[r][n] = winp[row * 16 + n];
            s_c[r][n] = proj[row * P_DIM + DT_RANK + D_STATE + n];
        }
        __syncthreads();
        for (int r = 0; r < 16; r++) {
            float dtv = s_dt[r][tid], uv = s_u[r][tid];
            float y = Dpd * uv;
#pragma unroll
            for (int n = 0; n < 16; n++) {
                float ba = __expf(dtv * Ad[n]);
                h[n] = fmaf(ba, h[n], s_w[r][n]);
                y = fmaf(h[n], s_c[r][n], y);
            }
            out[(b * SEQ + t0 + r) * D_MODEL + d] = y;
        }
    }
}

extern "C" void kernel_launch(void* const* d_in, const int* in_sizes, int n_in,
                              void* d_out, int out_size, void* d_ws, size_t ws_size,
                              hipStream_t stream) {
    const float* x     = (const float*)d_in[0];
    const float* w_in  = (const float*)d_in[1];
    const float* w_x   = (const float*)d_in[2];
    const float* w_dt  = (const float*)d_in[3];
    const float* b_dt  = (const float*)d_in[4];
    const float* A_log = (const float*)d_in[5];
    const float* Dp    = (const float*)d_in[6];
    float* out = (float*)d_out;

    char* ws = (char*)d_ws;
    unsigned short* xb   = (unsigned short*)(ws + 0);         // 8 MB  bf16 x
    unsigned short* wt   = (unsigned short*)(ws + 8388608);   // 2 MB  bf16 w_in^T
    float* xin           = (float*)(ws + 10485760);           // 16 MB
    float* proj          = (float*)(ws + 27262976);           // 1.5 MB
    float* dtb           = (float*)(ws + 28835840);           // 16 MB
    float* winp          = (float*)(ws + 45613056);           // 256 KB
    float* aneg          = (float*)(ws + 45875200);           // 64 KB

    k_aneg<<<64, 256, 0, stream>>>(A_log, aneg);
    k_convert_x<<<4096, 256, 0, stream>>>(x, xb, (M_TOTAL * D_MODEL) / 4);
    dim3 tb(32, 8), tg(32, 32);
    k_transpose_w<<<tg, tb, 0, stream>>>(w_in, wt);
    k_gemm1<<<1024, 256, 0, stream>>>(xb, wt, xin);
    k_proj<<<1024, 128, 0, stream>>>(xin, w_x, proj);
    k_dt<<<M_TOTAL, 256, 0, stream>>>(proj, w_dt, b_dt, dtb);
    k_winp<<<M_TOTAL, 256, 0, stream>>>(dtb, xin, aneg, proj, winp);
    k_scan<<<8, 256, 0, stream>>>(dtb, xin, winp, proj, aneg, Dp, out);
}

// Round 2
// 301.884 us; speedup vs baseline: 2.6316x; 2.6316x over previous
//
#include <hip/hip_runtime.h>
#include <hip/hip_bf16.h>

#define D_MODEL 1024
#define D_STATE 16
#define DT_RANK 64
#define SEQ 2048
#define BATCH 2
#define M_TOTAL (BATCH * SEQ) /* 4096 rows */
#define P_DIM 96              /* DT_RANK + 2*D_STATE */
#define CHUNKS 64
#define CLEN 32               /* SEQ / CHUNKS */

typedef __bf16 bf16x8 __attribute__((ext_vector_type(8)));
typedef float f32x4 __attribute__((ext_vector_type(4)));

__device__ __forceinline__ unsigned short f2bf(float f) {
    union { float f; unsigned int u; } v; v.f = f;
    unsigned int r = v.u + 0x7FFFu + ((v.u >> 16) & 1u);
    return (unsigned short)(r >> 16);
}

// ---------- K0: Aneg = -exp(A_log), (1024,16) ----------
__global__ void k_aneg(const float* __restrict__ alog, float* __restrict__ aneg) {
    int i = blockIdx.x * 256 + threadIdx.x;
    if (i < D_MODEL * D_STATE) aneg[i] = -expf(alog[i]);
}

// ---------- K1: x fp32 -> bf16 ----------
__global__ void k_convert_x(const float* __restrict__ x, unsigned short* __restrict__ xb, int n4) {
    int i = blockIdx.x * 256 + threadIdx.x;
    if (i >= n4) return;
    float4 v = reinterpret_cast<const float4*>(x)[i];
    ushort4 o;
    o.x = f2bf(v.x); o.y = f2bf(v.y); o.z = f2bf(v.z); o.w = f2bf(v.w);
    reinterpret_cast<ushort4*>(xb)[i] = o;
}

// ---------- K2: w_in (1024x1024) fp32 -> w_t bf16 transposed [n][k] ----------
__global__ void k_transpose_w(const float* __restrict__ w, unsigned short* __restrict__ wt) {
    __shared__ float tile[32][33];
    int tx = threadIdx.x, ty = threadIdx.y;
    int bx = blockIdx.x, by = blockIdx.y;
    int xc = bx * 32 + tx;
#pragma unroll
    for (int j = 0; j < 4; j++)
        tile[ty + 8 * j][tx] = w[(by * 32 + ty + 8 * j) * D_MODEL + xc];
    __syncthreads();
    int x2 = by * 32 + tx;
#pragma unroll
    for (int j = 0; j < 4; j++)
        wt[(bx * 32 + ty + 8 * j) * D_MODEL + x2] = f2bf(tile[tx][ty + 8 * j]);
}

// ---------- K3: x_in = x @ w_in via bf16 MFMA; per-wave 16x64 tile ----------
__global__ void __launch_bounds__(256) k_gemm1(const unsigned short* __restrict__ xb,
                                               const unsigned short* __restrict__ wt,
                                               float* __restrict__ xin) {
    int wid = blockIdx.x * 4 + (threadIdx.x >> 6);
    int lane = threadIdx.x & 63;
    int m0 = (wid & 255) * 16;  // M/16 = 256 tiles, fastest
    int n0 = (wid >> 8) * 64;   // N/64 = 16 groups
    int c = lane & 15, q = lane >> 4;
    f32x4 acc[4] = {};
    const unsigned short* pa = xb + (m0 + c) * D_MODEL + q * 8;
    const unsigned short* pb = wt + (n0 + c) * D_MODEL + q * 8;
    for (int k0 = 0; k0 < D_MODEL; k0 += 32) {
        bf16x8 a = *reinterpret_cast<const bf16x8*>(pa + k0);
#pragma unroll
        for (int t = 0; t < 4; t++) {
            bf16x8 b = *reinterpret_cast<const bf16x8*>(pb + t * 16 * D_MODEL + k0);
            acc[t] = __builtin_amdgcn_mfma_f32_16x16x32_bf16(a, b, acc[t], 0, 0, 0);
        }
    }
    // C/D layout: col = lane&15, row = (lane>>4)*4 + reg   [verified m89/m91]
#pragma unroll
    for (int t = 0; t < 4; t++)
#pragma unroll
        for (int r = 0; r < 4; r++)
            xin[(m0 + q * 4 + r) * D_MODEL + n0 + t * 16 + c] = acc[t][r];
}

// ---------- K4: proj = x_in @ w_x, (4096 x 96); 4 rows per block ----------
__global__ void __launch_bounds__(128) k_proj(const float* __restrict__ xin,
                                              const float* __restrict__ wx,
                                              float* __restrict__ proj) {
    __shared__ float xrow[4][D_MODEL];
    int m0 = blockIdx.x * 4;
    int tid = threadIdx.x;
#pragma unroll
    for (int rr = 0; rr < 4; rr++)
        for (int i = tid; i < D_MODEL; i += 128)
            xrow[rr][i] = xin[(m0 + rr) * D_MODEL + i];
    __syncthreads();
    if (tid < P_DIM) {
        float a0 = 0.f, a1 = 0.f, a2 = 0.f, a3 = 0.f;
        for (int k = 0; k < D_MODEL; k++) {
            float w = wx[k * P_DIM + tid];
            a0 = fmaf(xrow[0][k], w, a0);
            a1 = fmaf(xrow[1][k], w, a1);
            a2 = fmaf(xrow[2][k], w, a2);
            a3 = fmaf(xrow[3][k], w, a3);
        }
        proj[(m0 + 0) * P_DIM + tid] = a0;
        proj[(m0 + 1) * P_DIM + tid] = a1;
        proj[(m0 + 2) * P_DIM + tid] = a2;
        proj[(m0 + 3) * P_DIM + tid] = a3;
    }
}

// ---------- K5: dt = softplus(dt_low @ w_dt + b_dt)*0.099 + 0.001 ----------
__global__ void __launch_bounds__(256) k_dt(const float* __restrict__ proj,
                                            const float* __restrict__ wdt,
                                            const float* __restrict__ bdt,
                                            float* __restrict__ dt) {
    __shared__ float low[DT_RANK];
    int m = blockIdx.x, tid = threadIdx.x;
    if (tid < DT_RANK) low[tid] = proj[m * P_DIM + tid];
    __syncthreads();
    float acc[4] = {0.f, 0.f, 0.f, 0.f};
    for (int r = 0; r < DT_RANK; r++) {
        float v = low[r];
#pragma unroll
        for (int i = 0; i < 4; i++)
            acc[i] = fmaf(v, wdt[r * D_MODEL + tid + i * 256], acc[i]);
    }
#pragma unroll
    for (int i = 0; i < 4; i++) {
        int d = tid + i * 256;
        float xv = acc[i] + bdt[d];
        float sp = fmaxf(xv, 0.f) + log1pf(expf(-fabsf(xv)));
        dt[m * D_MODEL + d] = sp * 0.099f + 0.001f;
    }
}

// ---------- K6: winp[m,n] = B[m,n] * sum_d dt[m,d]*u[m,d]*Aneg[d,n] ----------
__global__ void __launch_bounds__(256) k_winp(const float* __restrict__ dt,
                                              const float* __restrict__ xin,
                                              const float* __restrict__ aneg,
                                              const float* __restrict__ proj,
                                              float* __restrict__ winp) {
    __shared__ float red[256][17];
    int m = blockIdx.x, tid = threadIdx.x;
    float part[16];
#pragma unroll
    for (int n = 0; n < 16; n++) part[n] = 0.f;
    for (int d = tid; d < D_MODEL; d += 256) {
        float g = dt[m * D_MODEL + d] * xin[m * D_MODEL + d];
        const float4* ar = reinterpret_cast<const float4*>(aneg + d * 16);
#pragma unroll
        for (int j = 0; j < 4; j++) {
            float4 a4 = ar[j];
            part[4 * j + 0] = fmaf(g, a4.x, part[4 * j + 0]);
            part[4 * j + 1] = fmaf(g, a4.y, part[4 * j + 1]);
            part[4 * j + 2] = fmaf(g, a4.z, part[4 * j + 2]);
            part[4 * j + 3] = fmaf(g, a4.w, part[4 * j + 3]);
        }
    }
#pragma unroll
    for (int n = 0; n < 16; n++) red[tid][n] = part[n];
    __syncthreads();
    for (int s = 128; s > 0; s >>= 1) {
        if (tid < s) {
#pragma unroll
            for (int n = 0; n < 16; n++) red[tid][n] += red[tid + s][n];
        }
        __syncthreads();
    }
    if (tid < 16) winp[m * 16 + tid] = proj[m * P_DIM + DT_RANK + tid] * red[0][tid];
}

// ---------- K7a: per-chunk local scan (h=0 init) -> h_loc[b,c,d,n], dtsum[b,c,d] ----------
__global__ void __launch_bounds__(256) k_scan1(const float* __restrict__ dt,
                                               const float* __restrict__ winp,
                                               const float* __restrict__ aneg,
                                               float* __restrict__ h_loc,
                                               float* __restrict__ dtsum) {
    __shared__ float s_dt[16][256];
    __shared__ float s_w[16][16];
    int dc = blockIdx.x & 3;
    int c = (blockIdx.x >> 2) & (CHUNKS - 1);
    int b = blockIdx.x >> 8;
    int tid = threadIdx.x;
    int d = dc * 256 + tid;
    float Ad[16];
    const float4* ar = reinterpret_cast<const float4*>(aneg + d * 16);
#pragma unroll
    for (int j = 0; j < 4; j++) {
        float4 a4 = ar[j];
        Ad[4 * j + 0] = a4.x; Ad[4 * j + 1] = a4.y;
        Ad[4 * j + 2] = a4.z; Ad[4 * j + 3] = a4.w;
    }
    float h[16];
#pragma unroll
    for (int n = 0; n < 16; n++) h[n] = 0.f;
    float dts = 0.f;

    for (int t0 = 0; t0 < CLEN; t0 += 16) {
        __syncthreads();
#pragma unroll
        for (int r = 0; r < 16; r++) {
            int row = b * SEQ + c * CLEN + t0 + r;
            s_dt[r][tid] = dt[row * D_MODEL + d];
        }
        {
            int r = tid >> 4, n = tid & 15;
            int row = b * SEQ + c * CLEN + t0 + r;
            s_w[r][n] = winp[row * 16 + n];
        }
        __syncthreads();
        for (int r = 0; r < 16; r++) {
            float dtv = s_dt[r][tid];
            dts += dtv;
#pragma unroll
            for (int n = 0; n < 16; n++) {
                float ba = __expf(dtv * Ad[n]);
                h[n] = fmaf(ba, h[n], s_w[r][n]);
            }
        }
    }
    int base = ((b * CHUNKS + c) * D_MODEL + d) * 16;
#pragma unroll
    for (int j = 0; j < 4; j++) {
        f32x4 v = {h[4 * j], h[4 * j + 1], h[4 * j + 2], h[4 * j + 3]};
        *reinterpret_cast<f32x4*>(h_loc + base + 4 * j) = v;
    }
    dtsum[(b * CHUNKS + c) * D_MODEL + d] = dts;
}

// ---------- K7b: combine chunks sequentially; in-place h_loc -> H_in ----------
__global__ void __launch_bounds__(256) k_scan2(float* __restrict__ h_inout,
                                               const float* __restrict__ dtsum,
                                               const float* __restrict__ aneg) {
    int idx = blockIdx.x * 256 + threadIdx.x;     // 32768 = b*16384 + d*16 + n
    int n = idx & 15;
    int d = (idx >> 4) & (D_MODEL - 1);
    int b = idx >> 14;
    float A = aneg[d * 16 + n];
    float H = 0.f;
    for (int c = 0; c < CHUNKS; c++) {
        int off = (b * CHUNKS + c) * D_MODEL + d;
        float hl = h_inout[off * 16 + n];          // read before overwrite
        float P = __expf(dtsum[off] * A);
        h_inout[off * 16 + n] = H;                 // chunk-entry state H_in
        H = fmaf(P, H, hl);
    }
}

// ---------- K7c: per-chunk scan with correct init; produce y ----------
__global__ void __launch_bounds__(256) k_scan3(const float* __restrict__ dt,
                                               const float* __restrict__ xin,
                                               const float* __restrict__ winp,
                                               const float* __restrict__ proj,
                                               const float* __restrict__ aneg,
                                               const float* __restrict__ dp,
                                               const float* __restrict__ H_in,
                                               float* __restrict__ out) {
    __shared__ float s_dt[16][256], s_u[16][256], s_w[16][16], s_c[16][16];
    int dc = blockIdx.x & 3;
    int c = (blockIdx.x >> 2) & (CHUNKS - 1);
    int b = blockIdx.x >> 8;
    int tid = threadIdx.x;
    int d = dc * 256 + tid;
    float Ad[16];
    const float4* ar = reinterpret_cast<const float4*>(aneg + d * 16);
#pragma unroll
    for (int j = 0; j < 4; j++) {
        float4 a4 = ar[j];
        Ad[4 * j + 0] = a4.x; Ad[4 * j + 1] = a4.y;
        Ad[4 * j + 2] = a4.z; Ad[4 * j + 3] = a4.w;
    }
    float Dpd = dp[d];
    float h[16];
    int base = ((b * CHUNKS + c) * D_MODEL + d) * 16;
#pragma unroll
    for (int j = 0; j < 4; j++) {
        f32x4 v = *reinterpret_cast<const f32x4*>(H_in + base + 4 * j);
        h[4 * j] = v[0]; h[4 * j + 1] = v[1]; h[4 * j + 2] = v[2]; h[4 * j + 3] = v[3];
    }

    for (int t0 = 0; t0 < CLEN; t0 += 16) {
        __syncthreads();
#pragma unroll
        for (int r = 0; r < 16; r++) {
            int row = b * SEQ + c * CLEN + t0 + r;
            s_dt[r][tid] = dt[row * D_MODEL + d];
            s_u[r][tid] = xin[row * D_MODEL + d];
        }
        {
            int r = tid >> 4, n = tid & 15;
            int row = b * SEQ + c * CLEN + t0 + r;
            s_w[r][n] = winp[row * 16 + n];
            s_c[r][n] = proj[row * P_DIM + DT_RANK + D_STATE + n];
        }
        __syncthreads();
        for (int r = 0; r < 16; r++) {
            float dtv = s_dt[r][tid], uv = s_u[r][tid];
            float y = Dpd * uv;
#pragma unroll
            for (int n = 0; n < 16; n++) {
                float ba = __expf(dtv * Ad[n]);
                h[n] = fmaf(ba, h[n], s_w[r][n]);
                y = fmaf(h[n], s_c[r][n], y);
            }
            out[(b * SEQ + c * CLEN + t0 + r) * D_MODEL + d] = y;
        }
    }
}

extern "C" void kernel_launch(void* const* d_in, const int* in_sizes, int n_in,
                              void* d_out, int out_size, void* d_ws, size_t ws_size,
                              hipStream_t stream) {
    const float* x     = (const float*)d_in[0];
    const float* w_in  = (const float*)d_in[1];
    const float* w_x   = (const float*)d_in[2];
    const float* w_dt  = (const float*)d_in[3];
    const float* b_dt  = (const float*)d_in[4];
    const float* A_log = (const float*)d_in[5];
    const float* Dp    = (const float*)d_in[6];
    float* out = (float*)d_out;

    char* ws = (char*)d_ws;
    unsigned short* xb   = (unsigned short*)(ws + 0);         // 8 MB  bf16 x (dead after gemm1)
    unsigned short* wt   = (unsigned short*)(ws + 8388608);   // 2 MB  bf16 w_in^T (dead after gemm1)
    float* xin           = (float*)(ws + 10485760);           // 16 MB
    float* proj          = (float*)(ws + 27262976);           // 1.5 MB
    float* dtb           = (float*)(ws + 28835840);           // 16 MB
    float* winp          = (float*)(ws + 45613056);           // 256 KB
    float* aneg          = (float*)(ws + 45875200);           // 64 KB
    // scan scratch overlays the dead xb/wt region:
    float* h_loc         = (float*)(ws + 0);                  // 8 MB  [b][c][d][n] (-> H_in in place)
    float* dtsum         = (float*)(ws + 8388608);            // 512 KB [b][c][d]

    k_aneg<<<64, 256, 0, stream>>>(A_log, aneg);
    k_convert_x<<<4096, 256, 0, stream>>>(x, xb, (M_TOTAL * D_MODEL) / 4);
    dim3 tb(32, 8), tg(32, 32);
    k_transpose_w<<<tg, tb, 0, stream>>>(w_in, wt);
    k_gemm1<<<1024, 256, 0, stream>>>(xb, wt, xin);
    k_proj<<<1024, 128, 0, stream>>>(xin, w_x, proj);
    k_dt<<<M_TOTAL, 256, 0, stream>>>(proj, w_dt, b_dt, dtb);
    k_winp<<<M_TOTAL, 256, 0, stream>>>(dtb, xin, aneg, proj, winp);
    k_scan1<<<BATCH * CHUNKS * 4, 256, 0, stream>>>(dtb, winp, aneg, h_loc, dtsum);
    k_scan2<<<128, 256, 0, stream>>>(h_loc, dtsum, aneg);
    k_scan3<<<BATCH * CHUNKS * 4, 256, 0, stream>>>(dtb, xin, winp, proj, aneg, Dp, h_loc, out);
}

// Round 3
// 282.853 us; speedup vs baseline: 2.8086x; 1.0673x over previous
//
#include <hip/hip_runtime.h>
#include <hip/hip_bf16.h>

#define D_MODEL 1024
#define D_STATE 16
#define DT_RANK 64
#define SEQ 2048
#define BATCH 2
#define M_TOTAL 4096
#define CHUNKS 64
#define CLEN 32
#define NB 2176 /* B^T rows: 1024 w_in + 1024 dt-combo + 32 BC + 96 pad(poison, masked) */

typedef __bf16 bf16x8 __attribute__((ext_vector_type(8)));
typedef float f32x4 __attribute__((ext_vector_type(4)));

__device__ __forceinline__ unsigned short f2bf(float f) {
    union { float f; unsigned int u; } v; v.f = f;
    unsigned int r = v.u + 0x7FFFu + ((v.u >> 16) & 1u);
    return (unsigned short)(r >> 16);
}
__device__ __forceinline__ float bf2f(unsigned short u) {
    union { unsigned int i; float f; } v; v.i = ((unsigned int)u) << 16; return v.f;
}
__device__ __forceinline__ void gload16(const void* g, void* l) {
    __builtin_amdgcn_global_load_lds(
        (const __attribute__((address_space(1))) unsigned int*)g,
        (__attribute__((address_space(3))) unsigned int*)l, 16, 0, 0);
}

// ---------- Aneg = -exp(A_log) ----------
__global__ void k_aneg(const float* __restrict__ alog, float* __restrict__ aneg) {
    int i = blockIdx.x * 256 + threadIdx.x;
    if (i < D_MODEL * D_STATE) aneg[i] = -expf(alog[i]);
}

// ---------- x fp32 -> bf16 ----------
__global__ void k_convert_x(const float* __restrict__ x, unsigned short* __restrict__ xb, int n4) {
    int i = blockIdx.x * 256 + threadIdx.x;
    if (i >= n4) return;
    float4 v = reinterpret_cast<const float4*>(x)[i];
    ushort4 o;
    o.x = f2bf(v.x); o.y = f2bf(v.y); o.z = f2bf(v.z); o.w = f2bf(v.w);
    reinterpret_cast<ushort4*>(xb)[i] = o;
}

// ---------- w_in -> bt rows 0..1023 (bf16, [e][d] = w_in[d][e]) ----------
__global__ void k_transpose_w(const float* __restrict__ w, unsigned short* __restrict__ bt) {
    __shared__ float tile[32][33];
    int tx = threadIdx.x, ty = threadIdx.y;
    int bx = blockIdx.x, by = blockIdx.y;
    int xc = bx * 32 + tx;
#pragma unroll
    for (int j = 0; j < 4; j++)
        tile[ty + 8 * j][tx] = w[(by * 32 + ty + 8 * j) * D_MODEL + xc];
    __syncthreads();
    int x2 = by * 32 + tx;
#pragma unroll
    for (int j = 0; j < 4; j++)
        bt[(bx * 32 + ty + 8 * j) * D_MODEL + x2] = f2bf(tile[tx][ty + 8 * j]);
}

// ---------- prep1: W_comb = w_in @ w_x (1024x96, contraction over e) ----------
// cols <64 -> Tt[r][d] fp32 ; cols 64..95 -> bt rows 2048..2079 bf16 (BC weights)
__global__ void __launch_bounds__(128) k_prep1(const float* __restrict__ win,
                                               const float* __restrict__ wx,
                                               float* __restrict__ Tt,
                                               unsigned short* __restrict__ bt) {
    __shared__ float xrow[4][D_MODEL];
    int m0 = blockIdx.x * 4;  // d rows of w_in
    int tid = threadIdx.x;
#pragma unroll
    for (int rr = 0; rr < 4; rr++)
        for (int i = tid; i < D_MODEL; i += 128)
            xrow[rr][i] = win[(m0 + rr) * D_MODEL + i];
    __syncthreads();
    if (tid < 96) {
        float a0 = 0.f, a1 = 0.f, a2 = 0.f, a3 = 0.f;
        for (int e = 0; e < D_MODEL; e++) {
            float wv = wx[e * 96 + tid];
            a0 = fmaf(xrow[0][e], wv, a0);
            a1 = fmaf(xrow[1][e], wv, a1);
            a2 = fmaf(xrow[2][e], wv, a2);
            a3 = fmaf(xrow[3][e], wv, a3);
        }
        if (tid < 64) {
            Tt[tid * D_MODEL + m0 + 0] = a0;
            Tt[tid * D_MODEL + m0 + 1] = a1;
            Tt[tid * D_MODEL + m0 + 2] = a2;
            Tt[tid * D_MODEL + m0 + 3] = a3;
        } else {
            int p = 2048 + (tid - 64);
            bt[p * D_MODEL + m0 + 0] = f2bf(a0);
            bt[p * D_MODEL + m0 + 1] = f2bf(a1);
            bt[p * D_MODEL + m0 + 2] = f2bf(a2);
            bt[p * D_MODEL + m0 + 3] = f2bf(a3);
        }
    }
}

// ---------- prep2: bt rows 1024..2047 = (Tt^T @ w_dt)^T bf16 ----------
// W_dtc^T[m][d] = sum_r w_dt[r][m] * Tt[r][d]
__global__ void __launch_bounds__(256) k_prep2(const float* __restrict__ wdt,
                                               const float* __restrict__ Tt,
                                               unsigned short* __restrict__ bt) {
    __shared__ float sw[DT_RANK][8];
    int m0 = blockIdx.x * 8;
    int tid = threadIdx.x;
    for (int s = tid; s < DT_RANK * 8; s += 256) {
        int r = s >> 3, rr = s & 7;
        sw[r][rr] = wdt[r * D_MODEL + m0 + rr];
    }
    __syncthreads();
    float acc[8][4] = {};
    for (int r = 0; r < DT_RANK; r++) {
        float tv0 = Tt[r * D_MODEL + tid];
        float tv1 = Tt[r * D_MODEL + tid + 256];
        float tv2 = Tt[r * D_MODEL + tid + 512];
        float tv3 = Tt[r * D_MODEL + tid + 768];
#pragma unroll
        for (int rr = 0; rr < 8; rr++) {
            float wv = sw[r][rr];
            acc[rr][0] = fmaf(wv, tv0, acc[rr][0]);
            acc[rr][1] = fmaf(wv, tv1, acc[rr][1]);
            acc[rr][2] = fmaf(wv, tv2, acc[rr][2]);
            acc[rr][3] = fmaf(wv, tv3, acc[rr][3]);
        }
    }
#pragma unroll
    for (int rr = 0; rr < 8; rr++)
#pragma unroll
        for (int i = 0; i < 4; i++)
            bt[(D_MODEL + m0 + rr) * D_MODEL + tid + i * 256] = f2bf(acc[rr][i]);
}

// ---------- big GEMM: (4096x1024) @ bt^T(2176x1024) ; m97 structure ----------
// epilogue: ntile<8 -> xin bf16 ; 8..15 -> softplus dt fp32 ; 16 -> bc fp32 (32 cols)
__global__ void __launch_bounds__(256) k_gemm_big(const unsigned short* __restrict__ xb,
                                                  const unsigned short* __restrict__ bt,
                                                  const float* __restrict__ bdt,
                                                  unsigned short* __restrict__ xinb,
                                                  float* __restrict__ dtb,
                                                  float* __restrict__ bc) {
    __shared__ unsigned short sA[128 * 32];
    __shared__ unsigned short sB[128 * 32];
    int bid = blockIdx.x;
    int m0 = (bid & 31) * 128;
    int nt = bid >> 5;  // 0..16
    int n0 = nt * 128;
    int t = threadIdx.x;
    int lane = t & 63;
    int wm = ((t >> 7) & 1) * 64;  // wave>>1
    int wn = ((t >> 6) & 1) * 64;  // wave&1
    int c = lane & 15, q = lane >> 4;

    f32x4 acc[4][4] = {};

    int srow = t >> 2;
    int scol = (t & 3) * 8;
    const unsigned short* ga = xb + (m0 + srow) * D_MODEL + scol;
    const unsigned short* gb = bt + (n0 + srow) * D_MODEL + scol;
    char* la = (char*)sA + (t & 192) * 16;  // wave-uniform: w*1024
    char* lb = (char*)sB + (t & 192) * 16;

    for (int k0 = 0; k0 < D_MODEL; k0 += 32) {
        __syncthreads();
        gload16(ga + k0, la);
        gload16(ga + 64 * D_MODEL + k0, la + 4096);
        gload16(gb + k0, lb);
        gload16(gb + 64 * D_MODEL + k0, lb + 4096);
        __syncthreads();
        bf16x8 af[4], bfr[4];
#pragma unroll
        for (int i = 0; i < 4; i++)
            af[i] = *reinterpret_cast<const bf16x8*>(sA + (wm + i * 16 + c) * 32 + q * 8);
#pragma unroll
        for (int j = 0; j < 4; j++)
            bfr[j] = *reinterpret_cast<const bf16x8*>(sB + (wn + j * 16 + c) * 32 + q * 8);
#pragma unroll
        for (int i = 0; i < 4; i++)
#pragma unroll
            for (int j = 0; j < 4; j++)
                acc[i][j] = __builtin_amdgcn_mfma_f32_16x16x32_bf16(af[i], bfr[j], acc[i][j], 0, 0, 0);
    }

    // C/D layout: col = lane&15, row = (lane>>4)*4 + reg   [m89/m91]
    if (nt < 8) {
#pragma unroll
        for (int i = 0; i < 4; i++) {
            int row = m0 + wm + i * 16 + q * 4;
#pragma unroll
            for (int j = 0; j < 4; j++) {
                int col = n0 + wn + j * 16 + c;
#pragma unroll
                for (int r = 0; r < 4; r++)
                    xinb[(row + r) * D_MODEL + col] = f2bf(acc[i][j][r]);
            }
        }
    } else if (nt < 16) {
#pragma unroll
        for (int i = 0; i < 4; i++) {
            int row = m0 + wm + i * 16 + q * 4;
#pragma unroll
            for (int j = 0; j < 4; j++) {
                int dcol = n0 + wn + j * 16 + c - D_MODEL;
                float bv = bdt[dcol];
#pragma unroll
                for (int r = 0; r < 4; r++) {
                    float xv = acc[i][j][r] + bv;
                    float sp = fmaxf(xv, 0.f) + log1pf(expf(-fabsf(xv)));
                    dtb[(row + r) * D_MODEL + dcol] = sp * 0.099f + 0.001f;
                }
            }
        }
    } else if (wn == 0) {  // BC tile: only cols 2048..2079 valid (j<2, wn==0)
#pragma unroll
        for (int i = 0; i < 4; i++) {
            int row = m0 + wm + i * 16 + q * 4;
#pragma unroll
            for (int j = 0; j < 2; j++) {
                int p = j * 16 + c;
#pragma unroll
                for (int r = 0; r < 4; r++)
                    bc[(row + r) * 32 + p] = acc[i][j][r];
            }
        }
    }
}

// ---------- winp[m,n] = B[m,n] * sum_d dt[m,d]*u[m,d]*Aneg[d,n] ----------
__global__ void __launch_bounds__(256) k_winp(const float* __restrict__ dt,
                                              const unsigned short* __restrict__ xinb,
                                              const float* __restrict__ aneg,
                                              const float* __restrict__ bc,
                                              float* __restrict__ winp) {
    __shared__ float red[256][17];
    int m = blockIdx.x, tid = threadIdx.x;
    float part[16];
#pragma unroll
    for (int n = 0; n < 16; n++) part[n] = 0.f;
    for (int d = tid; d < D_MODEL; d += 256) {
        float g = dt[m * D_MODEL + d] * bf2f(xinb[m * D_MODEL + d]);
        const float4* ar = reinterpret_cast<const float4*>(aneg + d * 16);
#pragma unroll
        for (int j = 0; j < 4; j++) {
            float4 a4 = ar[j];
            part[4 * j + 0] = fmaf(g, a4.x, part[4 * j + 0]);
            part[4 * j + 1] = fmaf(g, a4.y, part[4 * j + 1]);
            part[4 * j + 2] = fmaf(g, a4.z, part[4 * j + 2]);
            part[4 * j + 3] = fmaf(g, a4.w, part[4 * j + 3]);
        }
    }
#pragma unroll
    for (int n = 0; n < 16; n++) red[tid][n] = part[n];
    __syncthreads();
    for (int s = 128; s > 0; s >>= 1) {
        if (tid < s) {
#pragma unroll
            for (int n = 0; n < 16; n++) red[tid][n] += red[tid + s][n];
        }
        __syncthreads();
    }
    if (tid < 16) winp[m * 16 + tid] = bc[m * 32 + tid] * red[0][tid];
}

// ---------- scan phase 1: chunk-local scan -> h_loc, dtsum ----------
__global__ void __launch_bounds__(256) k_scan1(const float* __restrict__ dt,
                                               const float* __restrict__ winp,
                                               const float* __restrict__ aneg,
                                               float* __restrict__ h_loc,
                                               float* __restrict__ dtsum) {
    __shared__ float s_dt[16][256];
    __shared__ float s_w[16][16];
    int dc = blockIdx.x & 3;
    int c = (blockIdx.x >> 2) & (CHUNKS - 1);
    int b = blockIdx.x >> 8;
    int tid = threadIdx.x;
    int d = dc * 256 + tid;
    float Ad[16];
    const float4* ar = reinterpret_cast<const float4*>(aneg + d * 16);
#pragma unroll
    for (int j = 0; j < 4; j++) {
        float4 a4 = ar[j];
        Ad[4 * j + 0] = a4.x; Ad[4 * j + 1] = a4.y;
        Ad[4 * j + 2] = a4.z; Ad[4 * j + 3] = a4.w;
    }
    float h[16];
#pragma unroll
    for (int n = 0; n < 16; n++) h[n] = 0.f;
    float dts = 0.f;

    for (int t0 = 0; t0 < CLEN; t0 += 16) {
        __syncthreads();
#pragma unroll
        for (int r = 0; r < 16; r++) {
            int row = b * SEQ + c * CLEN + t0 + r;
            s_dt[r][tid] = dt[row * D_MODEL + d];
        }
        {
            int r = tid >> 4, n = tid & 15;
            int row = b * SEQ + c * CLEN + t0 + r;
            s_w[r][n] = winp[row * 16 + n];
        }
        __syncthreads();
        for (int r = 0; r < 16; r++) {
            float dtv = s_dt[r][tid];
            dts += dtv;
#pragma unroll
            for (int n = 0; n < 16; n++) {
                float ba = __expf(dtv * Ad[n]);
                h[n] = fmaf(ba, h[n], s_w[r][n]);
            }
        }
    }
    int base = ((b * CHUNKS + c) * D_MODEL + d) * 16;
#pragma unroll
    for (int j = 0; j < 4; j++) {
        f32x4 v = {h[4 * j], h[4 * j + 1], h[4 * j + 2], h[4 * j + 3]};
        *reinterpret_cast<f32x4*>(h_loc + base + 4 * j) = v;
    }
    dtsum[(b * CHUNKS + c) * D_MODEL + d] = dts;
}

// ---------- scan phase 2: combine chunks (prefetch-pipelined) ----------
__global__ void __launch_bounds__(256) k_scan2(float* __restrict__ h_inout,
                                               const float* __restrict__ dtsum,
                                               const float* __restrict__ aneg) {
    int idx = blockIdx.x * 256 + threadIdx.x;
    int n = idx & 15;
    int d = (idx >> 4) & (D_MODEL - 1);
    int b = idx >> 14;
    float A = aneg[d * 16 + n];
    float H = 0.f;
    int off = (b * CHUNKS) * D_MODEL + d;
    float hl = h_inout[off * 16 + n];
    float ds = dtsum[off];
    for (int c = 0; c < CHUNKS; c++) {
        int off2 = off + D_MODEL;
        float hl_n = 0.f, ds_n = 0.f;
        if (c + 1 < CHUNKS) { hl_n = h_inout[off2 * 16 + n]; ds_n = dtsum[off2]; }
        float P = __expf(ds * A);
        h_inout[off * 16 + n] = H;
        H = fmaf(P, H, hl);
        hl = hl_n; ds = ds_n; off = off2;
    }
}

// ---------- scan phase 3: chunk scan from H_in; emit y ----------
__global__ void __launch_bounds__(256) k_scan3(const float* __restrict__ dt,
                                               const unsigned short* __restrict__ xinb,
                                               const float* __restrict__ winp,
                                               const float* __restrict__ bc,
                                               const float* __restrict__ aneg,
                                               const float* __restrict__ dp,
                                               const float* __restrict__ H_in,
                                               float* __restrict__ out) {
    __shared__ float s_dt[16][256], s_u[16][256], s_w[16][16], s_c[16][16];
    int dc = blockIdx.x & 3;
    int c = (blockIdx.x >> 2) & (CHUNKS - 1);
    int b = blockIdx.x >> 8;
    int tid = threadIdx.x;
    int d = dc * 256 + tid;
    float Ad[16];
    const float4* ar = reinterpret_cast<const float4*>(aneg + d * 16);
#pragma unroll
    for (int j = 0; j < 4; j++) {
        float4 a4 = ar[j];
        Ad[4 * j + 0] = a4.x; Ad[4 * j + 1] = a4.y;
        Ad[4 * j + 2] = a4.z; Ad[4 * j + 3] = a4.w;
    }
    float Dpd = dp[d];
    float h[16];
    int base = ((b * CHUNKS + c) * D_MODEL + d) * 16;
#pragma unroll
    for (int j = 0; j < 4; j++) {
        f32x4 v = *reinterpret_cast<const f32x4*>(H_in + base + 4 * j);
        h[4 * j] = v[0]; h[4 * j + 1] = v[1]; h[4 * j + 2] = v[2]; h[4 * j + 3] = v[3];
    }

    for (int t0 = 0; t0 < CLEN; t0 += 16) {
        __syncthreads();
#pragma unroll
        for (int r = 0; r < 16; r++) {
            int row = b * SEQ + c * CLEN + t0 + r;
            s_dt[r][tid] = dt[row * D_MODEL + d];
            s_u[r][tid] = bf2f(xinb[row * D_MODEL + d]);
        }
        {
            int r = tid >> 4, n = tid & 15;
            int row = b * SEQ + c * CLEN + t0 + r;
            s_w[r][n] = winp[row * 16 + n];
            s_c[r][n] = bc[row * 32 + 16 + n];
        }
        __syncthreads();
        for (int r = 0; r < 16; r++) {
            float dtv = s_dt[r][tid], uv = s_u[r][tid];
            float y = Dpd * uv;
#pragma unroll
            for (int n = 0; n < 16; n++) {
                float ba = __expf(dtv * Ad[n]);
                h[n] = fmaf(ba, h[n], s_w[r][n]);
                y = fmaf(h[n], s_c[r][n], y);
            }
            out[(b * SEQ + c * CLEN + t0 + r) * D_MODEL + d] = y;
        }
    }
}

extern "C" void kernel_launch(void* const* d_in, const int* in_sizes, int n_in,
                              void* d_out, int out_size, void* d_ws, size_t ws_size,
                              hipStream_t stream) {
    const float* x     = (const float*)d_in[0];
    const float* w_in  = (const float*)d_in[1];
    const float* w_x   = (const float*)d_in[2];
    const float* w_dt  = (const float*)d_in[3];
    const float* b_dt  = (const float*)d_in[4];
    const float* A_log = (const float*)d_in[5];
    const float* Dp    = (const float*)d_in[6];
    float* out = (float*)d_out;

    char* ws = (char*)d_ws;
    unsigned short* xb   = (unsigned short*)(ws + 0);          // 8 MB (dead after gemm)
    unsigned short* bt   = (unsigned short*)(ws + 8388608);    // 4.25 MB (dead after gemm)
    float* Tt            = (float*)(ws + 12845056);            // 256 KB
    float* aneg          = (float*)(ws + 13107200);            // 64 KB
    float* bc            = (float*)(ws + 13172736);            // 512 KB
    float* winp          = (float*)(ws + 13697024);            // 256 KB
    unsigned short* xinb = (unsigned short*)(ws + 13959168);   // 8 MB
    float* dtb           = (float*)(ws + 22347776);            // 16 MB (ends 39.1 MB)
    // overlays of dead regions:
    float* h_loc         = (float*)(ws + 0);                   // 8 MB  [b][c][d][n]
    float* dtsum         = (float*)(ws + 8388608);             // 512 KB [b][c][d]

    k_aneg<<<64, 256, 0, stream>>>(A_log, aneg);
    k_convert_x<<<4096, 256, 0, stream>>>(x, xb, (M_TOTAL * D_MODEL) / 4);
    dim3 tb(32, 8), tg(32, 32);
    k_transpose_w<<<tg, tb, 0, stream>>>(w_in, bt);
    k_prep1<<<256, 128, 0, stream>>>(w_in, w_x, Tt, bt);
    k_prep2<<<128, 256, 0, stream>>>(w_dt, Tt, bt);
    k_gemm_big<<<544, 256, 0, stream>>>(xb, bt, b_dt, xinb, dtb, bc);
    k_winp<<<M_TOTAL, 256, 0, stream>>>(dtb, xinb, aneg, bc, winp);
    k_scan1<<<BATCH * CHUNKS * 4, 256, 0, stream>>>(dtb, winp, aneg, h_loc, dtsum);
    k_scan2<<<128, 256, 0, stream>>>(h_loc, dtsum, aneg);
    k_scan3<<<BATCH * CHUNKS * 4, 256, 0, stream>>>(dtb, xinb, winp, bc, aneg, Dp, h_loc, out);
}

// Round 4
// 271.903 us; speedup vs baseline: 2.9217x; 1.0403x over previous
//
#include <hip/hip_runtime.h>
#include <hip/hip_bf16.h>

#define D_MODEL 1024
#define D_STATE 16
#define DT_RANK 64
#define SEQ 2048
#define BATCH 2
#define M_TOTAL 4096
#define CHUNKS 64
#define CLEN 32

typedef __bf16 bf16x8 __attribute__((ext_vector_type(8)));
typedef float f32x4 __attribute__((ext_vector_type(4)));

__device__ __forceinline__ unsigned short f2bf(float f) {
    union { float f; unsigned int u; } v; v.f = f;
    unsigned int r = v.u + 0x7FFFu + ((v.u >> 16) & 1u);
    return (unsigned short)(r >> 16);
}
__device__ __forceinline__ float bf2f(unsigned short u) {
    union { unsigned int i; float f; } v; v.i = ((unsigned int)u) << 16; return v.f;
}
__device__ __forceinline__ void gload16(const void* g, void* l) {
    __builtin_amdgcn_global_load_lds(
        (const __attribute__((address_space(1))) unsigned int*)g,
        (__attribute__((address_space(3))) unsigned int*)l, 16, 0, 0);
}

// ---------- Aneg = -exp(A_log) ----------
__global__ void k_aneg(const float* __restrict__ alog, float* __restrict__ aneg) {
    int i = blockIdx.x * 256 + threadIdx.x;
    if (i < D_MODEL * D_STATE) aneg[i] = -expf(alog[i]);
}

// ---------- x fp32 -> bf16 ----------
__global__ void k_convert_x(const float* __restrict__ x, unsigned short* __restrict__ xb, int n4) {
    int i = blockIdx.x * 256 + threadIdx.x;
    if (i >= n4) return;
    float4 v = reinterpret_cast<const float4*>(x)[i];
    ushort4 o;
    o.x = f2bf(v.x); o.y = f2bf(v.y); o.z = f2bf(v.z); o.w = f2bf(v.w);
    reinterpret_cast<ushort4*>(xb)[i] = o;
}

// ---------- w_in -> bt rows 0..1023 (bf16, [e][d] = w_in[d][e]) ----------
__global__ void k_transpose_w(const float* __restrict__ w, unsigned short* __restrict__ bt) {
    __shared__ float tile[32][33];
    int tx = threadIdx.x, ty = threadIdx.y;
    int bx = blockIdx.x, by = blockIdx.y;
    int xc = bx * 32 + tx;
#pragma unroll
    for (int j = 0; j < 4; j++)
        tile[ty + 8 * j][tx] = w[(by * 32 + ty + 8 * j) * D_MODEL + xc];
    __syncthreads();
    int x2 = by * 32 + tx;
#pragma unroll
    for (int j = 0; j < 4; j++)
        bt[(bx * 32 + ty + 8 * j) * D_MODEL + x2] = f2bf(tile[tx][ty + 8 * j]);
}

// ---------- prep1: W_comb = w_in @ w_x (1024x96); 4-way e-split ----------
// cols <64 -> Tt[r][d] fp32 ; cols 64..95 -> bt rows 2048..2079 bf16
__global__ void __launch_bounds__(384) k_prep1(const float* __restrict__ win,
                                               const float* __restrict__ wx,
                                               float* __restrict__ Tt,
                                               unsigned short* __restrict__ bt) {
    __shared__ float xrow[4][D_MODEL];
    __shared__ float part[4][4][96];
    int m0 = blockIdx.x * 4;
    int tid = threadIdx.x;
    for (int i = tid; i < 4 * D_MODEL; i += 384)
        xrow[i >> 10][i & 1023] = win[(m0 + (i >> 10)) * D_MODEL + (i & 1023)];
    __syncthreads();
    int col = tid % 96;
    int eq = tid / 96;  // 0..3
    float a0 = 0.f, a1 = 0.f, a2 = 0.f, a3 = 0.f;
    int e0 = eq * 256;
    for (int e = e0; e < e0 + 256; e++) {
        float wv = wx[e * 96 + col];
        a0 = fmaf(xrow[0][e], wv, a0);
        a1 = fmaf(xrow[1][e], wv, a1);
        a2 = fmaf(xrow[2][e], wv, a2);
        a3 = fmaf(xrow[3][e], wv, a3);
    }
    part[eq][0][col] = a0; part[eq][1][col] = a1;
    part[eq][2][col] = a2; part[eq][3][col] = a3;
    __syncthreads();
    if (eq == 0) {
#pragma unroll
        for (int rr = 0; rr < 4; rr++) {
            float s = part[0][rr][col] + part[1][rr][col] + part[2][rr][col] + part[3][rr][col];
            if (col < 64)
                Tt[col * D_MODEL + m0 + rr] = s;
            else
                bt[(2048 + col - 64) * D_MODEL + m0 + rr] = f2bf(s);
        }
    }
}

// ---------- prep2: bt rows 1024..2047 = (Tt^T @ w_dt)^T bf16 ----------
__global__ void __launch_bounds__(256) k_prep2(const float* __restrict__ wdt,
                                               const float* __restrict__ Tt,
                                               unsigned short* __restrict__ bt) {
    __shared__ float sw[DT_RANK][8];
    int m0 = blockIdx.x * 8;
    int tid = threadIdx.x;
    for (int s = tid; s < DT_RANK * 8; s += 256) {
        int r = s >> 3, rr = s & 7;
        sw[r][rr] = wdt[r * D_MODEL + m0 + rr];
    }
    __syncthreads();
    float acc[8][4] = {};
    for (int r = 0; r < DT_RANK; r++) {
        float tv0 = Tt[r * D_MODEL + tid];
        float tv1 = Tt[r * D_MODEL + tid + 256];
        float tv2 = Tt[r * D_MODEL + tid + 512];
        float tv3 = Tt[r * D_MODEL + tid + 768];
#pragma unroll
        for (int rr = 0; rr < 8; rr++) {
            float wv = sw[r][rr];
            acc[rr][0] = fmaf(wv, tv0, acc[rr][0]);
            acc[rr][1] = fmaf(wv, tv1, acc[rr][1]);
            acc[rr][2] = fmaf(wv, tv2, acc[rr][2]);
            acc[rr][3] = fmaf(wv, tv3, acc[rr][3]);
        }
    }
#pragma unroll
    for (int rr = 0; rr < 8; rr++)
#pragma unroll
        for (int i = 0; i < 4; i++)
            bt[(D_MODEL + m0 + rr) * D_MODEL + tid + i * 256] = f2bf(acc[rr][i]);
}

// ---------- big GEMM: (4096x1024) @ bt^T(2176x1024); 64x128 tile, LDS dbuf ----------
// epilogue: nt<8 -> xin bf16 ; 8..15 -> softplus dt fp32 ; 16 -> bc fp32 (32 cols)
__global__ void __launch_bounds__(256) k_gemm_big(const unsigned short* __restrict__ xb,
                                                  const unsigned short* __restrict__ bt,
                                                  const float* __restrict__ bdt,
                                                  unsigned short* __restrict__ xinb,
                                                  float* __restrict__ dtb,
                                                  float* __restrict__ bc) {
    __shared__ unsigned short sA[2][64 * 32];   //  4 KB x2
    __shared__ unsigned short sB[2][128 * 32];  //  8 KB x2
    int bid = blockIdx.x;
    int m0 = (bid & 63) * 64;  // M fastest: 64 consecutive blocks share B-tile
    int nt = bid >> 6;         // 0..16
    int n0 = nt * 128;
    int t = threadIdx.x;
    int lane = t & 63;
    int w = t >> 6;            // wave id = n-strip (w*32)
    int c = lane & 15, q = lane >> 4;

    const unsigned short* ga = xb + (m0 + (t >> 2)) * D_MODEL + (t & 3) * 8;
    const unsigned short* gb = bt + (n0 + (t >> 2)) * D_MODEL + (t & 3) * 8;

    f32x4 acc[4][2] = {};

    // prologue: fill buffer 0 with k=0 tile
    {
        char* la = (char*)&sA[0][0] + w * 1024;
        char* lb = (char*)&sB[0][0] + w * 1024;
        gload16(ga, la);
        gload16(gb, lb);
        gload16(gb + 64 * D_MODEL, lb + 4096);
    }

    int cur = 0;
    for (int it = 0; it < 32; it++) {
        __syncthreads();  // drains fill(cur) via vmcnt(0); protects nxt buf reuse via lgkmcnt
        if (it + 1 < 32) {
            int kn = (it + 1) * 32;
            char* la = (char*)&sA[cur ^ 1][0] + w * 1024;
            char* lb = (char*)&sB[cur ^ 1][0] + w * 1024;
            gload16(ga + kn, la);
            gload16(gb + kn, lb);
            gload16(gb + 64 * D_MODEL + kn, lb + 4096);
        }
        bf16x8 af[4], bfr[2];
#pragma unroll
        for (int i = 0; i < 4; i++)
            af[i] = *reinterpret_cast<const bf16x8*>(&sA[cur][(i * 16 + c) * 32 + q * 8]);
#pragma unroll
        for (int j = 0; j < 2; j++)
            bfr[j] = *reinterpret_cast<const bf16x8*>(&sB[cur][(w * 32 + j * 16 + c) * 32 + q * 8]);
#pragma unroll
        for (int i = 0; i < 4; i++)
#pragma unroll
            for (int j = 0; j < 2; j++)
                acc[i][j] = __builtin_amdgcn_mfma_f32_16x16x32_bf16(af[i], bfr[j], acc[i][j], 0, 0, 0);
        cur ^= 1;
    }

    // C/D layout: col = lane&15, row = (lane>>4)*4 + reg   [m89/m91]
    if (nt < 8) {
#pragma unroll
        for (int i = 0; i < 4; i++) {
            int row = m0 + i * 16 + q * 4;
#pragma unroll
            for (int j = 0; j < 2; j++) {
                int col = n0 + w * 32 + j * 16 + c;
#pragma unroll
                for (int r = 0; r < 4; r++)
                    xinb[(row + r) * D_MODEL + col] = f2bf(acc[i][j][r]);
            }
        }
    } else if (nt < 16) {
#pragma unroll
        for (int i = 0; i < 4; i++) {
            int row = m0 + i * 16 + q * 4;
#pragma unroll
            for (int j = 0; j < 2; j++) {
                int dcol = n0 + w * 32 + j * 16 + c - D_MODEL;
                float bv = bdt[dcol];
#pragma unroll
                for (int r = 0; r < 4; r++) {
                    float xv = acc[i][j][r] + bv;
                    float sp = fmaxf(xv, 0.f) + __logf(1.f + __expf(-fabsf(xv)));
                    dtb[(row + r) * D_MODEL + dcol] = sp * 0.099f + 0.001f;
                }
            }
        }
    } else if (w == 0) {  // BC tile: only cols 2048..2079 valid
#pragma unroll
        for (int i = 0; i < 4; i++) {
            int row = m0 + i * 16 + q * 4;
#pragma unroll
            for (int j = 0; j < 2; j++) {
                int p = j * 16 + c;
#pragma unroll
                for (int r = 0; r < 4; r++)
                    bc[(row + r) * 32 + p] = acc[i][j][r];
            }
        }
    }
}

// ---------- winp[m,n] = B[m,n] * sum_d dt[m,d]*u[m,d]*Aneg[d,n]; 2 rows/block ----------
__global__ void __launch_bounds__(256) k_winp(const float* __restrict__ dt,
                                              const unsigned short* __restrict__ xinb,
                                              const float* __restrict__ aneg,
                                              const float* __restrict__ bc,
                                              float* __restrict__ winp) {
    __shared__ float r0[16][17], r1[16][17];
    int m = blockIdx.x * 2;
    int tid = threadIdx.x;
    int n = tid & 15, strip = tid >> 4;  // 16 strips x 64 d
    float a0 = 0.f, a1 = 0.f;
    int d0 = strip * 64;
    for (int dd = 0; dd < 64; dd++) {
        int d = d0 + dd;
        float g0 = dt[m * D_MODEL + d] * bf2f(xinb[m * D_MODEL + d]);
        float g1 = dt[(m + 1) * D_MODEL + d] * bf2f(xinb[(m + 1) * D_MODEL + d]);
        float av = aneg[d * 16 + n];
        a0 = fmaf(g0, av, a0);
        a1 = fmaf(g1, av, a1);
    }
    r0[strip][n] = a0; r1[strip][n] = a1;
    __syncthreads();
    for (int s = 8; s > 0; s >>= 1) {
        if (strip < s) {
            r0[strip][n] += r0[strip + s][n];
            r1[strip][n] += r1[strip + s][n];
        }
        __syncthreads();
    }
    if (tid < 16) winp[m * 16 + n] = bc[m * 32 + n] * r0[0][n];
    else if (tid < 32) winp[(m + 1) * 16 + n] = bc[(m + 1) * 32 + n] * r1[0][n];
}

// ---------- scan phase 1: chunk-local scan -> h_loc, dtsum ----------
__global__ void __launch_bounds__(256) k_scan1(const float* __restrict__ dt,
                                               const float* __restrict__ winp,
                                               const float* __restrict__ aneg,
                                               float* __restrict__ h_loc,
                                               float* __restrict__ dtsum) {
    __shared__ float s_dt[16][256];
    __shared__ float s_w[16][16];
    int dc = blockIdx.x & 3;
    int c = (blockIdx.x >> 2) & (CHUNKS - 1);
    int b = blockIdx.x >> 8;
    int tid = threadIdx.x;
    int d = dc * 256 + tid;
    float Ad[16];
    const float4* ar = reinterpret_cast<const float4*>(aneg + d * 16);
#pragma unroll
    for (int j = 0; j < 4; j++) {
        float4 a4 = ar[j];
        Ad[4 * j + 0] = a4.x; Ad[4 * j + 1] = a4.y;
        Ad[4 * j + 2] = a4.z; Ad[4 * j + 3] = a4.w;
    }
    float h[16];
#pragma unroll
    for (int n = 0; n < 16; n++) h[n] = 0.f;
    float dts = 0.f;

    for (int t0 = 0; t0 < CLEN; t0 += 16) {
        __syncthreads();
#pragma unroll
        for (int r = 0; r < 16; r++) {
            int row = b * SEQ + c * CLEN + t0 + r;
            s_dt[r][tid] = dt[row * D_MODEL + d];
        }
        {
            int r = tid >> 4, n = tid & 15;
            int row = b * SEQ + c * CLEN + t0 + r;
            s_w[r][n] = winp[row * 16 + n];
        }
        __syncthreads();
        for (int r = 0; r < 16; r++) {
            float dtv = s_dt[r][tid];
            dts += dtv;
#pragma unroll
            for (int n = 0; n < 16; n++) {
                float ba = __expf(dtv * Ad[n]);
                h[n] = fmaf(ba, h[n], s_w[r][n]);
            }
        }
    }
    int base = ((b * CHUNKS + c) * D_MODEL + d) * 16;
#pragma unroll
    for (int j = 0; j < 4; j++) {
        f32x4 v = {h[4 * j], h[4 * j + 1], h[4 * j + 2], h[4 * j + 3]};
        *reinterpret_cast<f32x4*>(h_loc + base + 4 * j) = v;
    }
    dtsum[(b * CHUNKS + c) * D_MODEL + d] = dts;
}

// ---------- scan phase 2: combine chunks (prefetch-pipelined) ----------
__global__ void __launch_bounds__(256) k_scan2(float* __restrict__ h_inout,
                                               const float* __restrict__ dtsum,
                                               const float* __restrict__ aneg) {
    int idx = blockIdx.x * 256 + threadIdx.x;
    int n = idx & 15;
    int d = (idx >> 4) & (D_MODEL - 1);
    int b = idx >> 14;
    float A = aneg[d * 16 + n];
    float H = 0.f;
    int off = (b * CHUNKS) * D_MODEL + d;
    float hl = h_inout[off * 16 + n];
    float ds = dtsum[off];
    for (int c = 0; c < CHUNKS; c++) {
        int off2 = off + D_MODEL;
        float hl_n = 0.f, ds_n = 0.f;
        if (c + 1 < CHUNKS) { hl_n = h_inout[off2 * 16 + n]; ds_n = dtsum[off2]; }
        float P = __expf(ds * A);
        h_inout[off * 16 + n] = H;
        H = fmaf(P, H, hl);
        hl = hl_n; ds = ds_n; off = off2;
    }
}

// ---------- scan phase 3: chunk scan from H_in; emit y ----------
__global__ void __launch_bounds__(256) k_scan3(const float* __restrict__ dt,
                                               const unsigned short* __restrict__ xinb,
                                               const float* __restrict__ winp,
                                               const float* __restrict__ bc,
                                               const float* __restrict__ aneg,
                                               const float* __restrict__ dp,
                                               const float* __restrict__ H_in,
                                               float* __restrict__ out) {
    __shared__ float s_dt[16][256], s_u[16][256], s_w[16][16], s_c[16][16];
    int dc = blockIdx.x & 3;
    int c = (blockIdx.x >> 2) & (CHUNKS - 1);
    int b = blockIdx.x >> 8;
    int tid = threadIdx.x;
    int d = dc * 256 + tid;
    float Ad[16];
    const float4* ar = reinterpret_cast<const float4*>(aneg + d * 16);
#pragma unroll
    for (int j = 0; j < 4; j++) {
        float4 a4 = ar[j];
        Ad[4 * j + 0] = a4.x; Ad[4 * j + 1] = a4.y;
        Ad[4 * j + 2] = a4.z; Ad[4 * j + 3] = a4.w;
    }
    float Dpd = dp[d];
    float h[16];
    int base = ((b * CHUNKS + c) * D_MODEL + d) * 16;
#pragma unroll
    for (int j = 0; j < 4; j++) {
        f32x4 v = *reinterpret_cast<const f32x4*>(H_in + base + 4 * j);
        h[4 * j] = v[0]; h[4 * j + 1] = v[1]; h[4 * j + 2] = v[2]; h[4 * j + 3] = v[3];
    }

    for (int t0 = 0; t0 < CLEN; t0 += 16) {
        __syncthreads();
#pragma unroll
        for (int r = 0; r < 16; r++) {
            int row = b * SEQ + c * CLEN + t0 + r;
            s_dt[r][tid] = dt[row * D_MODEL + d];
            s_u[r][tid] = bf2f(xinb[row * D_MODEL + d]);
        }
        {
            int r = tid >> 4, n = tid & 15;
            int row = b * SEQ + c * CLEN + t0 + r;
            s_w[r][n] = winp[row * 16 + n];
            s_c[r][n] = bc[row * 32 + 16 + n];
        }
        __syncthreads();
        for (int r = 0; r < 16; r++) {
            float dtv = s_dt[r][tid], uv = s_u[r][tid];
            float y = Dpd * uv;
#pragma unroll
            for (int n = 0; n < 16; n++) {
                float ba = __expf(dtv * Ad[n]);
                h[n] = fmaf(ba, h[n], s_w[r][n]);
                y = fmaf(h[n], s_c[r][n], y);
            }
            out[(b * SEQ + c * CLEN + t0 + r) * D_MODEL + d] = y;
        }
    }
}

extern "C" void kernel_launch(void* const* d_in, const int* in_sizes, int n_in,
                              void* d_out, int out_size, void* d_ws, size_t ws_size,
                              hipStream_t stream) {
    const float* x     = (const float*)d_in[0];
    const float* w_in  = (const float*)d_in[1];
    const float* w_x   = (const float*)d_in[2];
    const float* w_dt  = (const float*)d_in[3];
    const float* b_dt  = (const float*)d_in[4];
    const float* A_log = (const float*)d_in[5];
    const float* Dp    = (const float*)d_in[6];
    float* out = (float*)d_out;

    char* ws = (char*)d_ws;
    unsigned short* xb   = (unsigned short*)(ws + 0);          // 8 MB (dead after gemm)
    unsigned short* bt   = (unsigned short*)(ws + 8388608);    // 4.25 MB (dead after gemm)
    float* Tt            = (float*)(ws + 12845056);            // 256 KB
    float* aneg          = (float*)(ws + 13107200);            // 64 KB
    float* bc            = (float*)(ws + 13172736);            // 512 KB
    float* winp          = (float*)(ws + 13697024);            // 256 KB
    unsigned short* xinb = (unsigned short*)(ws + 13959168);   // 8 MB
    float* dtb           = (float*)(ws + 22347776);            // 16 MB
    // overlays of dead regions:
    float* h_loc         = (float*)(ws + 0);                   // 8 MB  [b][c][d][n]
    float* dtsum         = (float*)(ws + 8388608);             // 512 KB [b][c][d]

    k_aneg<<<64, 256, 0, stream>>>(A_log, aneg);
    k_convert_x<<<4096, 256, 0, stream>>>(x, xb, (M_TOTAL * D_MODEL) / 4);
    dim3 tb(32, 8), tg(32, 32);
    k_transpose_w<<<tg, tb, 0, stream>>>(w_in, bt);
    k_prep1<<<256, 384, 0, stream>>>(w_in, w_x, Tt, bt);
    k_prep2<<<128, 256, 0, stream>>>(w_dt, Tt, bt);
    k_gemm_big<<<1088, 256, 0, stream>>>(xb, bt, b_dt, xinb, dtb, bc);
    k_winp<<<2048, 256, 0, stream>>>(dtb, xinb, aneg, bc, winp);
    k_scan1<<<BATCH * CHUNKS * 4, 256, 0, stream>>>(dtb, winp, aneg, h_loc, dtsum);
    k_scan2<<<128, 256, 0, stream>>>(h_loc, dtsum, aneg);
    k_scan3<<<BATCH * CHUNKS * 4, 256, 0, stream>>>(dtb, xinb, winp, bc, aneg, Dp, h_loc, out);
}

// Round 6
// 216.486 us; speedup vs baseline: 3.6697x; 1.2560x over previous
//
#include <hip/hip_runtime.h>
#include <hip/hip_bf16.h>

#define D_MODEL 1024
#define D_STATE 16
#define DT_RANK 64
#define SEQ 2048
#define BATCH 2
#define M_TOTAL 4096
#define CHUNKS 64
#define CLEN 32

typedef __bf16 bf16x8 __attribute__((ext_vector_type(8)));
typedef float f32x4 __attribute__((ext_vector_type(4)));

__device__ __forceinline__ unsigned short f2bf(float f) {
    union { float f; unsigned int u; } v; v.f = f;
    unsigned int r = v.u + 0x7FFFu + ((v.u >> 16) & 1u);
    return (unsigned short)(r >> 16);
}
__device__ __forceinline__ float bf2f(unsigned short u) {
    union { unsigned int i; float f; } v; v.i = ((unsigned int)u) << 16; return v.f;
}
__device__ __forceinline__ void gload16(const void* g, void* l) {
    __builtin_amdgcn_global_load_lds(
        (const __attribute__((address_space(1))) unsigned int*)g,
        (__attribute__((address_space(3))) unsigned int*)l, 16, 0, 0);
}

// ---------- Aneg = -exp(A_log) ----------
__global__ void k_aneg(const float* __restrict__ alog, float* __restrict__ aneg) {
    int i = blockIdx.x * 256 + threadIdx.x;
    if (i < D_MODEL * D_STATE) aneg[i] = -expf(alog[i]);
}

// ---------- fp32 -> bf16 (generic, float4) ----------
__global__ void k_convert(const float* __restrict__ x, unsigned short* __restrict__ xb, int n4) {
    int i = blockIdx.x * 256 + threadIdx.x;
    if (i >= n4) return;
    float4 v = reinterpret_cast<const float4*>(x)[i];
    ushort4 o;
    o.x = f2bf(v.x); o.y = f2bf(v.y); o.z = f2bf(v.z); o.w = f2bf(v.w);
    reinterpret_cast<ushort4*>(xb)[i] = o;
}

// ---------- w_in -> bt rows 0..1023 (bf16, [e][d] = w_in[d][e]) ----------
__global__ void k_transpose_w(const float* __restrict__ w, unsigned short* __restrict__ bt) {
    __shared__ float tile[32][33];
    int tx = threadIdx.x, ty = threadIdx.y;
    int bx = blockIdx.x, by = blockIdx.y;
    int xc = bx * 32 + tx;
#pragma unroll
    for (int j = 0; j < 4; j++)
        tile[ty + 8 * j][tx] = w[(by * 32 + ty + 8 * j) * D_MODEL + xc];
    __syncthreads();
    int x2 = by * 32 + tx;
#pragma unroll
    for (int j = 0; j < 4; j++)
        bt[(bx * 32 + ty + 8 * j) * D_MODEL + x2] = f2bf(tile[tx][ty + 8 * j]);
}

// ---------- w_x (1024x96) -> wxT (128x1024 bf16, rows 96..127 zero) ----------
__global__ void k_transpose_wx(const float* __restrict__ wx, unsigned short* __restrict__ wxT) {
    int idx = blockIdx.x * 256 + threadIdx.x;  // 131072
    int e = idx & 1023;
    int p = idx >> 10;
    wxT[p * D_MODEL + e] = (p < 96) ? f2bf(wx[e * 96 + p]) : (unsigned short)0;
}

// ---------- prep GEMM: Cp[ks][p][d] partials of (w_x^T @ w_in), 64x128 tile, K=256/block ----------
__global__ void __launch_bounds__(256) k_prepgemm(const unsigned short* __restrict__ wxT,
                                                  const unsigned short* __restrict__ wib,
                                                  float* __restrict__ Cp) {
    __shared__ unsigned short sA[2][64 * 32];
    __shared__ unsigned short sB[2][128 * 32];
    int bid = blockIdx.x;      // 64 = 2 m x 8 n x 4 ksplit
    int m0 = (bid & 1) * 64;
    int n0 = ((bid >> 1) & 7) * 128;
    int ks = bid >> 4;
    int kbase = ks * 256;
    int t = threadIdx.x;
    int lane = t & 63;
    int w = t >> 6;
    int c = lane & 15, q = lane >> 4;

    const unsigned short* ga = wxT + (m0 + (t >> 2)) * D_MODEL + (t & 3) * 8 + kbase;
    const unsigned short* gb = wib + (n0 + (t >> 2)) * D_MODEL + (t & 3) * 8 + kbase;

    f32x4 acc[4][2] = {};
    {
        char* la = (char*)&sA[0][0] + w * 1024;
        char* lb = (char*)&sB[0][0] + w * 1024;
        gload16(ga, la);
        gload16(gb, lb);
        gload16(gb + 64 * D_MODEL, lb + 4096);
    }
    int cur = 0;
    for (int it = 0; it < 8; it++) {
        __syncthreads();
        if (it + 1 < 8) {
            int kn = (it + 1) * 32;
            char* la = (char*)&sA[cur ^ 1][0] + w * 1024;
            char* lb = (char*)&sB[cur ^ 1][0] + w * 1024;
            gload16(ga + kn, la);
            gload16(gb + kn, lb);
            gload16(gb + 64 * D_MODEL + kn, lb + 4096);
        }
        bf16x8 af[4], bfr[2];
#pragma unroll
        for (int i = 0; i < 4; i++)
            af[i] = *reinterpret_cast<const bf16x8*>(&sA[cur][(i * 16 + c) * 32 + q * 8]);
#pragma unroll
        for (int j = 0; j < 2; j++)
            bfr[j] = *reinterpret_cast<const bf16x8*>(&sB[cur][(w * 32 + j * 16 + c) * 32 + q * 8]);
#pragma unroll
        for (int i = 0; i < 4; i++)
#pragma unroll
            for (int j = 0; j < 2; j++)
                acc[i][j] = __builtin_amdgcn_mfma_f32_16x16x32_bf16(af[i], bfr[j], acc[i][j], 0, 0, 0);
        cur ^= 1;
    }
#pragma unroll
    for (int i = 0; i < 4; i++) {
        int p = m0 + i * 16 + q * 4;
#pragma unroll
        for (int j = 0; j < 2; j++) {
            int d = n0 + w * 32 + j * 16 + c;
#pragma unroll
            for (int r = 0; r < 4; r++)
                Cp[(ks * 128 + p + r) * D_MODEL + d] = acc[i][j][r];
        }
    }
}

// ---------- prep reduce: sum 4 K-split partials -> Tt (p<64) / bt BC rows (64<=p<96) ----------
// second grid half zeroes bt rows 2080..2175 (read by gemm nt=16 tile, else unwritten)
__global__ void __launch_bounds__(256) k_prepreduce(const float* __restrict__ Cp,
                                                    float* __restrict__ Tt,
                                                    unsigned short* __restrict__ bt) {
    int idx = blockIdx.x * 256 + threadIdx.x;  // 0 .. 2*96*1024-1
    if (idx < 96 * 1024) {
        int d = idx & 1023;
        int p = idx >> 10;
        float s = Cp[p * D_MODEL + d] + Cp[(128 + p) * D_MODEL + d] +
                  Cp[(256 + p) * D_MODEL + d] + Cp[(384 + p) * D_MODEL + d];
        if (p < 64)
            Tt[p * D_MODEL + d] = s;
        else
            bt[(2048 + p - 64) * D_MODEL + d] = f2bf(s);
    } else {
        int j = idx - 96 * 1024;
        bt[(2080 + (j >> 10)) * D_MODEL + (j & 1023)] = 0;
    }
}

// ---------- prep2: bt rows 1024..2047 = (Tt^T @ w_dt)^T bf16 ----------
__global__ void __launch_bounds__(256) k_prep2(const float* __restrict__ wdt,
                                               const float* __restrict__ Tt,
                                               unsigned short* __restrict__ bt) {
    __shared__ float sw[DT_RANK][8];
    int m0 = blockIdx.x * 8;
    int tid = threadIdx.x;
    for (int s = tid; s < DT_RANK * 8; s += 256) {
        int r = s >> 3, rr = s & 7;
        sw[r][rr] = wdt[r * D_MODEL + m0 + rr];
    }
    __syncthreads();
    float acc[8][4] = {};
    for (int r = 0; r < DT_RANK; r++) {
        float tv0 = Tt[r * D_MODEL + tid];
        float tv1 = Tt[r * D_MODEL + tid + 256];
        float tv2 = Tt[r * D_MODEL + tid + 512];
        float tv3 = Tt[r * D_MODEL + tid + 768];
#pragma unroll
        for (int rr = 0; rr < 8; rr++) {
            float wv = sw[r][rr];
            acc[rr][0] = fmaf(wv, tv0, acc[rr][0]);
            acc[rr][1] = fmaf(wv, tv1, acc[rr][1]);
            acc[rr][2] = fmaf(wv, tv2, acc[rr][2]);
            acc[rr][3] = fmaf(wv, tv3, acc[rr][3]);
        }
    }
#pragma unroll
    for (int rr = 0; rr < 8; rr++)
#pragma unroll
        for (int i = 0; i < 4; i++)
            bt[(D_MODEL + m0 + rr) * D_MODEL + tid + i * 256] = f2bf(acc[rr][i]);
}

// ---------- big GEMM: (4096x1024) @ bt^T(2176x1024); 64x128 tile, LDS dbuf ----------
__global__ void __launch_bounds__(256) k_gemm_big(const unsigned short* __restrict__ xb,
                                                  const unsigned short* __restrict__ bt,
                                                  const float* __restrict__ bdt,
                                                  unsigned short* __restrict__ xinb,
                                                  float* __restrict__ dtb,
                                                  float* __restrict__ bc) {
    __shared__ unsigned short sA[2][64 * 32];
    __shared__ unsigned short sB[2][128 * 32];
    int bid = blockIdx.x;
    int m0 = (bid & 63) * 64;
    int nt = bid >> 6;  // 0..16
    int n0 = nt * 128;
    int t = threadIdx.x;
    int lane = t & 63;
    int w = t >> 6;
    int c = lane & 15, q = lane >> 4;

    const unsigned short* ga = xb + (m0 + (t >> 2)) * D_MODEL + (t & 3) * 8;
    const unsigned short* gb = bt + (n0 + (t >> 2)) * D_MODEL + (t & 3) * 8;

    f32x4 acc[4][2] = {};
    {
        char* la = (char*)&sA[0][0] + w * 1024;
        char* lb = (char*)&sB[0][0] + w * 1024;
        gload16(ga, la);
        gload16(gb, lb);
        gload16(gb + 64 * D_MODEL, lb + 4096);
    }
    int cur = 0;
    for (int it = 0; it < 32; it++) {
        __syncthreads();
        if (it + 1 < 32) {
            int kn = (it + 1) * 32;
            char* la = (char*)&sA[cur ^ 1][0] + w * 1024;
            char* lb = (char*)&sB[cur ^ 1][0] + w * 1024;
            gload16(ga + kn, la);
            gload16(gb + kn, lb);
            gload16(gb + 64 * D_MODEL + kn, lb + 4096);
        }
        bf16x8 af[4], bfr[2];
#pragma unroll
        for (int i = 0; i < 4; i++)
            af[i] = *reinterpret_cast<const bf16x8*>(&sA[cur][(i * 16 + c) * 32 + q * 8]);
#pragma unroll
        for (int j = 0; j < 2; j++)
            bfr[j] = *reinterpret_cast<const bf16x8*>(&sB[cur][(w * 32 + j * 16 + c) * 32 + q * 8]);
#pragma unroll
        for (int i = 0; i < 4; i++)
#pragma unroll
            for (int j = 0; j < 2; j++)
                acc[i][j] = __builtin_amdgcn_mfma_f32_16x16x32_bf16(af[i], bfr[j], acc[i][j], 0, 0, 0);
        cur ^= 1;
    }

    if (nt < 8) {
#pragma unroll
        for (int i = 0; i < 4; i++) {
            int row = m0 + i * 16 + q * 4;
#pragma unroll
            for (int j = 0; j < 2; j++) {
                int col = n0 + w * 32 + j * 16 + c;
#pragma unroll
                for (int r = 0; r < 4; r++)
                    xinb[(row + r) * D_MODEL + col] = f2bf(acc[i][j][r]);
            }
        }
    } else if (nt < 16) {
#pragma unroll
        for (int i = 0; i < 4; i++) {
            int row = m0 + i * 16 + q * 4;
#pragma unroll
            for (int j = 0; j < 2; j++) {
                int dcol = n0 + w * 32 + j * 16 + c - D_MODEL;
                float bv = bdt[dcol];
#pragma unroll
                for (int r = 0; r < 4; r++) {
                    float xv = acc[i][j][r] + bv;
                    float sp = fmaxf(xv, 0.f) + __logf(1.f + __expf(-fabsf(xv)));
                    dtb[(row + r) * D_MODEL + dcol] = sp * 0.099f + 0.001f;
                }
            }
        }
    } else if (w == 0) {
#pragma unroll
        for (int i = 0; i < 4; i++) {
            int row = m0 + i * 16 + q * 4;
#pragma unroll
            for (int j = 0; j < 2; j++) {
                int p = j * 16 + c;
#pragma unroll
                for (int r = 0; r < 4; r++)
                    bc[(row + r) * 32 + p] = acc[i][j][r];
            }
        }
    }
}

// ---------- winp[m,n] = B[m,n] * sum_d dt[m,d]*u[m,d]*Aneg[d,n]; 2 rows/block ----------
__global__ void __launch_bounds__(256) k_winp(const float* __restrict__ dt,
                                              const unsigned short* __restrict__ xinb,
                                              const float* __restrict__ aneg,
                                              const float* __restrict__ bc,
                                              float* __restrict__ winp) {
    __shared__ float r0[16][17], r1[16][17];
    int m = blockIdx.x * 2;
    int tid = threadIdx.x;
    int n = tid & 15, strip = tid >> 4;
    float a0 = 0.f, a1 = 0.f;
    int d0 = strip * 64;
    for (int dd = 0; dd < 64; dd++) {
        int d = d0 + dd;
        float g0 = dt[m * D_MODEL + d] * bf2f(xinb[m * D_MODEL + d]);
        float g1 = dt[(m + 1) * D_MODEL + d] * bf2f(xinb[(m + 1) * D_MODEL + d]);
        float av = aneg[d * 16 + n];
        a0 = fmaf(g0, av, a0);
        a1 = fmaf(g1, av, a1);
    }
    r0[strip][n] = a0; r1[strip][n] = a1;
    __syncthreads();
    for (int s = 8; s > 0; s >>= 1) {
        if (strip < s) {
            r0[strip][n] += r0[strip + s][n];
            r1[strip][n] += r1[strip + s][n];
        }
        __syncthreads();
    }
    if (tid < 16) winp[m * 16 + n] = bc[m * 32 + n] * r0[0][n];
    else if (tid < 32) winp[(m + 1) * 16 + n] = bc[(m + 1) * 32 + n] * r1[0][n];
}

// ---------- scan phase 1: chunk-local scan -> h_loc, dtsum ----------
__global__ void __launch_bounds__(256) k_scan1(const float* __restrict__ dt,
                                               const float* __restrict__ winp,
                                               const float* __restrict__ aneg,
                                               float* __restrict__ h_loc,
                                               float* __restrict__ dtsum) {
    __shared__ float s_dt[16][256];
    __shared__ float s_w[16][16];
    int dc = blockIdx.x & 3;
    int c = (blockIdx.x >> 2) & (CHUNKS - 1);
    int b = blockIdx.x >> 8;
    int tid = threadIdx.x;
    int d = dc * 256 + tid;
    float Ad[16];
    const float4* ar = reinterpret_cast<const float4*>(aneg + d * 16);
#pragma unroll
    for (int j = 0; j < 4; j++) {
        float4 a4 = ar[j];
        Ad[4 * j + 0] = a4.x; Ad[4 * j + 1] = a4.y;
        Ad[4 * j + 2] = a4.z; Ad[4 * j + 3] = a4.w;
    }
    float h[16];
#pragma unroll
    for (int n = 0; n < 16; n++) h[n] = 0.f;
    float dts = 0.f;

    for (int t0 = 0; t0 < CLEN; t0 += 16) {
        __syncthreads();
#pragma unroll
        for (int r = 0; r < 16; r++) {
            int row = b * SEQ + c * CLEN + t0 + r;
            s_dt[r][tid] = dt[row * D_MODEL + d];
        }
        {
            int r = tid >> 4, n = tid & 15;
            int row = b * SEQ + c * CLEN + t0 + r;
            s_w[r][n] = winp[row * 16 + n];
        }
        __syncthreads();
        for (int r = 0; r < 16; r++) {
            float dtv = s_dt[r][tid];
            dts += dtv;
#pragma unroll
            for (int n = 0; n < 16; n++) {
                float ba = __expf(dtv * Ad[n]);
                h[n] = fmaf(ba, h[n], s_w[r][n]);
            }
        }
    }
    int base = ((b * CHUNKS + c) * D_MODEL + d) * 16;
#pragma unroll
    for (int j = 0; j < 4; j++) {
        f32x4 v = {h[4 * j], h[4 * j + 1], h[4 * j + 2], h[4 * j + 3]};
        *reinterpret_cast<f32x4*>(h_loc + base + 4 * j) = v;
    }
    dtsum[(b * CHUNKS + c) * D_MODEL + d] = dts;
}

// ---------- scan phase 2: combine chunks (prefetch-pipelined) ----------
__global__ void __launch_bounds__(256) k_scan2(float* __restrict__ h_inout,
                                               const float* __restrict__ dtsum,
                                               const float* __restrict__ aneg) {
    int idx = blockIdx.x * 256 + threadIdx.x;
    int n = idx & 15;
    int d = (idx >> 4) & (D_MODEL - 1);
    int b = idx >> 14;
    float A = aneg[d * 16 + n];
    float H = 0.f;
    int off = (b * CHUNKS) * D_MODEL + d;
    float hl = h_inout[off * 16 + n];
    float ds = dtsum[off];
    for (int c = 0; c < CHUNKS; c++) {
        int off2 = off + D_MODEL;
        float hl_n = 0.f, ds_n = 0.f;
        if (c + 1 < CHUNKS) { hl_n = h_inout[off2 * 16 + n]; ds_n = dtsum[off2]; }
        float P = __expf(ds * A);
        h_inout[off * 16 + n] = H;
        H = fmaf(P, H, hl);
        hl = hl_n; ds = ds_n; off = off2;
    }
}

// ---------- scan phase 3: chunk scan from H_in; emit y ----------
__global__ void __launch_bounds__(256) k_scan3(const float* __restrict__ dt,
                                               const unsigned short* __restrict__ xinb,
                                               const float* __restrict__ winp,
                                               const float* __restrict__ bc,
                                               const float* __restrict__ aneg,
                                               const float* __restrict__ dp,
                                               const float* __restrict__ H_in,
                                               float* __restrict__ out) {
    __shared__ float s_dt[16][256], s_u[16][256], s_w[16][16], s_c[16][16];
    int dc = blockIdx.x & 3;
    int c = (blockIdx.x >> 2) & (CHUNKS - 1);
    int b = blockIdx.x >> 8;
    int tid = threadIdx.x;
    int d = dc * 256 + tid;
    float Ad[16];
    const float4* ar = reinterpret_cast<const float4*>(aneg + d * 16);
#pragma unroll
    for (int j = 0; j < 4; j++) {
        float4 a4 = ar[j];
        Ad[4 * j + 0] = a4.x; Ad[4 * j + 1] = a4.y;
        Ad[4 * j + 2] = a4.z; Ad[4 * j + 3] = a4.w;
    }
    float Dpd = dp[d];
    float h[16];
    int base = ((b * CHUNKS + c) * D_MODEL + d) * 16;
#pragma unroll
    for (int j = 0; j < 4; j++) {
        f32x4 v = *reinterpret_cast<const f32x4*>(H_in + base + 4 * j);
        h[4 * j] = v[0]; h[4 * j + 1] = v[1]; h[4 * j + 2] = v[2]; h[4 * j + 3] = v[3];
    }

    for (int t0 = 0; t0 < CLEN; t0 += 16) {
        __syncthreads();
#pragma unroll
        for (int r = 0; r < 16; r++) {
            int row = b * SEQ + c * CLEN + t0 + r;
            s_dt[r][tid] = dt[row * D_MODEL + d];
            s_u[r][tid] = bf2f(xinb[row * D_MODEL + d]);
        }
        {
            int r = tid >> 4, n = tid & 15;
            int row = b * SEQ + c * CLEN + t0 + r;
            s_w[r][n] = winp[row * 16 + n];
            s_c[r][n] = bc[row * 32 + 16 + n];
        }
        __syncthreads();
        for (int r = 0; r < 16; r++) {
            float dtv = s_dt[r][tid], uv = s_u[r][tid];
            float y = Dpd * uv;
#pragma unroll
            for (int n = 0; n < 16; n++) {
                float ba = __expf(dtv * Ad[n]);
                h[n] = fmaf(ba, h[n], s_w[r][n]);
                y = fmaf(h[n], s_c[r][n], y);
            }
            out[(b * SEQ + c * CLEN + t0 + r) * D_MODEL + d] = y;
        }
    }
}

extern "C" void kernel_launch(void* const* d_in, const int* in_sizes, int n_in,
                              void* d_out, int out_size, void* d_ws, size_t ws_size,
                              hipStream_t stream) {
    const float* x     = (const float*)d_in[0];
    const float* w_in  = (const float*)d_in[1];
    const float* w_x   = (const float*)d_in[2];
    const float* w_dt  = (const float*)d_in[3];
    const float* b_dt  = (const float*)d_in[4];
    const float* A_log = (const float*)d_in[5];
    const float* Dp    = (const float*)d_in[6];
    float* out = (float*)d_out;

    char* ws = (char*)d_ws;
    // footprint capped at 39124992 B (proven safe in round 3)
    unsigned short* xb   = (unsigned short*)(ws + 0);          // 8 MB (dead after gemm)
    unsigned short* bt   = (unsigned short*)(ws + 8388608);    // 4.25 MB (dead after gemm)
    float* Tt            = (float*)(ws + 12845056);            // 256 KB
    float* aneg          = (float*)(ws + 13107200);            // 64 KB
    float* bc            = (float*)(ws + 13172736);            // 512 KB
    float* winp          = (float*)(ws + 13697024);            // 256 KB
    unsigned short* xinb = (unsigned short*)(ws + 13959168);   // 8 MB
    float* dtb           = (float*)(ws + 22347776);            // 16 MB -> ends 39124992
    // prep-phase buffers overlay the dtb region (dead until gemm_big writes dtb):
    unsigned short* wib  = (unsigned short*)(ws + 22347776);   // 2 MB   bf16 w_in row-major
    unsigned short* wxT  = (unsigned short*)(ws + 24444928);   // 256 KB bf16 w_x^T (128x1024)
    float* Cp            = (float*)(ws + 24707072);            // 2 MB   K-split partials
    // scan-phase overlays of dead xb/bt regions:
    float* h_loc         = (float*)(ws + 0);                   // 8 MB  [b][c][d][n]
    float* dtsum         = (float*)(ws + 8388608);             // 512 KB [b][c][d]

    k_aneg<<<64, 256, 0, stream>>>(A_log, aneg);
    k_convert<<<4096, 256, 0, stream>>>(x, xb, (M_TOTAL * D_MODEL) / 4);
    k_convert<<<1024, 256, 0, stream>>>(w_in, wib, (D_MODEL * D_MODEL) / 4);
    dim3 tb(32, 8), tg(32, 32);
    k_transpose_w<<<tg, tb, 0, stream>>>(w_in, bt);
    k_transpose_wx<<<512, 256, 0, stream>>>(w_x, wxT);
    k_prepgemm<<<64, 256, 0, stream>>>(wxT, wib, Cp);
    k_prepreduce<<<768, 256, 0, stream>>>(Cp, Tt, bt);
    k_prep2<<<128, 256, 0, stream>>>(w_dt, Tt, bt);
    k_gemm_big<<<1088, 256, 0, stream>>>(xb, bt, b_dt, xinb, dtb, bc);
    k_winp<<<2048, 256, 0, stream>>>(dtb, xinb, aneg, bc, winp);
    k_scan1<<<BATCH * CHUNKS * 4, 256, 0, stream>>>(dtb, winp, aneg, h_loc, dtsum);
    k_scan2<<<128, 256, 0, stream>>>(h_loc, dtsum, aneg);
    k_scan3<<<BATCH * CHUNKS * 4, 256, 0, stream>>>(dtb, xinb, winp, bc, aneg, Dp, h_loc, out);
}

// Round 7
// 199.008 us; speedup vs baseline: 3.9919x; 1.0878x over previous
//
#include <hip/hip_runtime.h>
#include <hip/hip_bf16.h>

#define D_MODEL 1024
#define D_STATE 16
#define DT_RANK 64
#define SEQ 2048
#define BATCH 2
#define M_TOTAL 4096
#define CHUNKS 64
#define CLEN 32

typedef __bf16 bf16x8 __attribute__((ext_vector_type(8)));
typedef float f32x4 __attribute__((ext_vector_type(4)));

__device__ __forceinline__ unsigned short f2bf(float f) {
    union { float f; unsigned int u; } v; v.f = f;
    unsigned int r = v.u + 0x7FFFu + ((v.u >> 16) & 1u);
    return (unsigned short)(r >> 16);
}
__device__ __forceinline__ float bf2f(unsigned short u) {
    union { unsigned int i; float f; } v; v.i = ((unsigned int)u) << 16; return v.f;
}
__device__ __forceinline__ void gload16(const void* g, void* l) {
    __builtin_amdgcn_global_load_lds(
        (const __attribute__((address_space(1))) unsigned int*)g,
        (__attribute__((address_space(3))) unsigned int*)l, 16, 0, 0);
}

// ---------- fused setup: convert x, convert w_in, transpose w_in, transpose w_x, aneg ----------
__global__ void __launch_bounds__(256) k_setup(const float* __restrict__ x,
                                               const float* __restrict__ win,
                                               const float* __restrict__ wx,
                                               const float* __restrict__ alog,
                                               unsigned short* __restrict__ xb,
                                               unsigned short* __restrict__ wib,
                                               unsigned short* __restrict__ bt,
                                               unsigned short* __restrict__ wxT,
                                               float* __restrict__ aneg) {
    __shared__ float tile[32][33];
    int blk = blockIdx.x;
    int t = threadIdx.x;
    if (blk < 4096) {  // x fp32 -> bf16
        int i = blk * 256 + t;
        float4 v = reinterpret_cast<const float4*>(x)[i];
        ushort4 o;
        o.x = f2bf(v.x); o.y = f2bf(v.y); o.z = f2bf(v.z); o.w = f2bf(v.w);
        reinterpret_cast<ushort4*>(xb)[i] = o;
    } else if (blk < 5120) {  // w_in fp32 -> bf16 row-major
        int i = (blk - 4096) * 256 + t;
        float4 v = reinterpret_cast<const float4*>(win)[i];
        ushort4 o;
        o.x = f2bf(v.x); o.y = f2bf(v.y); o.z = f2bf(v.z); o.w = f2bf(v.w);
        reinterpret_cast<ushort4*>(wib)[i] = o;
    } else if (blk < 6144) {  // w_in^T -> bt rows 0..1023
        int blk2 = blk - 5120;
        int bx = blk2 & 31, by = blk2 >> 5;
        int tx = t & 31, ty = t >> 5;
        int xc = bx * 32 + tx;
#pragma unroll
        for (int j = 0; j < 4; j++)
            tile[ty + 8 * j][tx] = win[(by * 32 + ty + 8 * j) * D_MODEL + xc];
        __syncthreads();
        int x2 = by * 32 + tx;
#pragma unroll
        for (int j = 0; j < 4; j++)
            bt[(bx * 32 + ty + 8 * j) * D_MODEL + x2] = f2bf(tile[tx][ty + 8 * j]);
    } else if (blk < 6656) {  // w_x^T (128x1024, rows 96..127 zero)
        int idx = (blk - 6144) * 256 + t;
        int e = idx & 1023, p = idx >> 10;
        wxT[p * D_MODEL + e] = (p < 96) ? f2bf(wx[e * 96 + p]) : (unsigned short)0;
    } else {  // aneg = -exp(A_log)
        int i = (blk - 6656) * 256 + t;
        if (i < D_MODEL * D_STATE) aneg[i] = -expf(alog[i]);
    }
}

// ---------- prep GEMM: Cp[ks][p][d] partials of (w_x^T @ w_in), 64x128 tile, K=256/block ----------
__global__ void __launch_bounds__(256) k_prepgemm(const unsigned short* __restrict__ wxT,
                                                  const unsigned short* __restrict__ wib,
                                                  float* __restrict__ Cp) {
    __shared__ unsigned short sA[2][64 * 32];
    __shared__ unsigned short sB[2][128 * 32];
    int bid = blockIdx.x;      // 64 = 2 m x 8 n x 4 ksplit
    int m0 = (bid & 1) * 64;
    int n0 = ((bid >> 1) & 7) * 128;
    int ks = bid >> 4;
    int kbase = ks * 256;
    int t = threadIdx.x;
    int lane = t & 63;
    int w = t >> 6;
    int c = lane & 15, q = lane >> 4;

    const unsigned short* ga = wxT + (m0 + (t >> 2)) * D_MODEL + (t & 3) * 8 + kbase;
    const unsigned short* gb = wib + (n0 + (t >> 2)) * D_MODEL + (t & 3) * 8 + kbase;

    f32x4 acc[4][2] = {};
    {
        char* la = (char*)&sA[0][0] + w * 1024;
        char* lb = (char*)&sB[0][0] + w * 1024;
        gload16(ga, la);
        gload16(gb, lb);
        gload16(gb + 64 * D_MODEL, lb + 4096);
    }
    int cur = 0;
    for (int it = 0; it < 8; it++) {
        __syncthreads();
        if (it + 1 < 8) {
            int kn = (it + 1) * 32;
            char* la = (char*)&sA[cur ^ 1][0] + w * 1024;
            char* lb = (char*)&sB[cur ^ 1][0] + w * 1024;
            gload16(ga + kn, la);
            gload16(gb + kn, lb);
            gload16(gb + 64 * D_MODEL + kn, lb + 4096);
        }
        bf16x8 af[4], bfr[2];
#pragma unroll
        for (int i = 0; i < 4; i++)
            af[i] = *reinterpret_cast<const bf16x8*>(&sA[cur][(i * 16 + c) * 32 + q * 8]);
#pragma unroll
        for (int j = 0; j < 2; j++)
            bfr[j] = *reinterpret_cast<const bf16x8*>(&sB[cur][(w * 32 + j * 16 + c) * 32 + q * 8]);
#pragma unroll
        for (int i = 0; i < 4; i++)
#pragma unroll
            for (int j = 0; j < 2; j++)
                acc[i][j] = __builtin_amdgcn_mfma_f32_16x16x32_bf16(af[i], bfr[j], acc[i][j], 0, 0, 0);
        cur ^= 1;
    }
#pragma unroll
    for (int i = 0; i < 4; i++) {
        int p = m0 + i * 16 + q * 4;
#pragma unroll
        for (int j = 0; j < 2; j++) {
            int d = n0 + w * 32 + j * 16 + c;
#pragma unroll
            for (int r = 0; r < 4; r++)
                Cp[(ks * 128 + p + r) * D_MODEL + d] = acc[i][j][r];
        }
    }
}

// ---------- prep reduce: sum K-split partials -> Tt / bt BC rows; zero bt rows 2080.. ----------
__global__ void __launch_bounds__(256) k_prepreduce(const float* __restrict__ Cp,
                                                    float* __restrict__ Tt,
                                                    unsigned short* __restrict__ bt) {
    int idx = blockIdx.x * 256 + threadIdx.x;
    if (idx < 96 * 1024) {
        int d = idx & 1023;
        int p = idx >> 10;
        float s = Cp[p * D_MODEL + d] + Cp[(128 + p) * D_MODEL + d] +
                  Cp[(256 + p) * D_MODEL + d] + Cp[(384 + p) * D_MODEL + d];
        if (p < 64)
            Tt[p * D_MODEL + d] = s;
        else
            bt[(2048 + p - 64) * D_MODEL + d] = f2bf(s);
    } else {
        int j = idx - 96 * 1024;
        bt[(2080 + (j >> 10)) * D_MODEL + (j & 1023)] = 0;
    }
}

// ---------- prep2: bt rows 1024..2047 = (Tt^T @ w_dt)^T bf16 ----------
__global__ void __launch_bounds__(256) k_prep2(const float* __restrict__ wdt,
                                               const float* __restrict__ Tt,
                                               unsigned short* __restrict__ bt) {
    __shared__ float sw[DT_RANK][8];
    int m0 = blockIdx.x * 8;
    int tid = threadIdx.x;
    for (int s = tid; s < DT_RANK * 8; s += 256) {
        int r = s >> 3, rr = s & 7;
        sw[r][rr] = wdt[r * D_MODEL + m0 + rr];
    }
    __syncthreads();
    float acc[8][4] = {};
    for (int r = 0; r < DT_RANK; r++) {
        float tv0 = Tt[r * D_MODEL + tid];
        float tv1 = Tt[r * D_MODEL + tid + 256];
        float tv2 = Tt[r * D_MODEL + tid + 512];
        float tv3 = Tt[r * D_MODEL + tid + 768];
#pragma unroll
        for (int rr = 0; rr < 8; rr++) {
            float wv = sw[r][rr];
            acc[rr][0] = fmaf(wv, tv0, acc[rr][0]);
            acc[rr][1] = fmaf(wv, tv1, acc[rr][1]);
            acc[rr][2] = fmaf(wv, tv2, acc[rr][2]);
            acc[rr][3] = fmaf(wv, tv3, acc[rr][3]);
        }
    }
#pragma unroll
    for (int rr = 0; rr < 8; rr++)
#pragma unroll
        for (int i = 0; i < 4; i++)
            bt[(D_MODEL + m0 + rr) * D_MODEL + tid + i * 256] = f2bf(acc[rr][i]);
}

// ---------- big GEMM: 64x128 tile, BK=64, dbuf, XOR-swizzled LDS ----------
// LDS slot s (16B): row = s>>3, chunk = (s&7)^(row&7). Frag read at perm = (kk*4+q)^(c&7).
__global__ void __launch_bounds__(256) k_gemm_big(const unsigned short* __restrict__ xb,
                                                  const unsigned short* __restrict__ bt,
                                                  const float* __restrict__ bdt,
                                                  unsigned short* __restrict__ xinb,
                                                  float* __restrict__ dtb,
                                                  float* __restrict__ bc) {
    __shared__ unsigned short sA[2][64 * 64];   //  8 KB x2
    __shared__ unsigned short sB[2][128 * 64];  // 16 KB x2
    int bid = blockIdx.x;
    int m0 = (bid & 63) * 64;  // M fastest: consecutive blocks share B-tile in L2
    int nt = bid >> 6;         // 0..16
    int n0 = nt * 128;
    int t = threadIdx.x;
    int lane = t & 63;
    int w = t >> 6;
    int c = lane & 15, q = lane >> 4;

    // per-thread global gather pointers for the swizzled slots
    int sa0 = t, sa1 = t + 256;
    const unsigned short* gA0 = xb + (m0 + (sa0 >> 3)) * D_MODEL + ((((sa0 & 7) ^ ((sa0 >> 3) & 7))) << 3);
    const unsigned short* gA1 = xb + (m0 + (sa1 >> 3)) * D_MODEL + ((((sa1 & 7) ^ ((sa1 >> 3) & 7))) << 3);
    const unsigned short* gB0 = bt + (n0 + (sa0 >> 3)) * D_MODEL + ((((sa0 & 7) ^ ((sa0 >> 3) & 7))) << 3);
    const unsigned short* gB1 = bt + (n0 + (sa1 >> 3)) * D_MODEL + ((((sa1 & 7) ^ ((sa1 >> 3) & 7))) << 3);
    int sb2 = t + 512, sb3 = t + 768;
    const unsigned short* gB2 = bt + (n0 + (sb2 >> 3)) * D_MODEL + ((((sb2 & 7) ^ ((sb2 >> 3) & 7))) << 3);
    const unsigned short* gB3 = bt + (n0 + (sb3 >> 3)) * D_MODEL + ((((sb3 & 7) ^ ((sb3 >> 3) & 7))) << 3);

    f32x4 acc[4][2] = {};

    // prologue: fill buffer 0 (k-window 0)
    {
        char* la = (char*)&sA[0][0] + w * 1024;
        char* lb = (char*)&sB[0][0] + w * 1024;
        gload16(gA0, la);
        gload16(gA1, la + 4096);
        gload16(gB0, lb);
        gload16(gB1, lb + 4096);
        gload16(gB2, lb + 8192);
        gload16(gB3, lb + 12288);
    }

    int cur = 0;
    for (int it = 0; it < 16; it++) {
        __syncthreads();
        if (it + 1 < 16) {
            int kn = (it + 1) * 64;
            char* la = (char*)&sA[cur ^ 1][0] + w * 1024;
            char* lb = (char*)&sB[cur ^ 1][0] + w * 1024;
            gload16(gA0 + kn, la);
            gload16(gA1 + kn, la + 4096);
            gload16(gB0 + kn, lb);
            gload16(gB1 + kn, lb + 4096);
            gload16(gB2 + kn, lb + 8192);
            gload16(gB3 + kn, lb + 12288);
        }
#pragma unroll
        for (int kk = 0; kk < 2; kk++) {
            int perm = (((kk << 2) | q) ^ (c & 7)) << 3;
            bf16x8 af[4], bfr[2];
#pragma unroll
            for (int i = 0; i < 4; i++)
                af[i] = *reinterpret_cast<const bf16x8*>(&sA[cur][(i * 16 + c) * 64 + perm]);
#pragma unroll
            for (int j = 0; j < 2; j++)
                bfr[j] = *reinterpret_cast<const bf16x8*>(&sB[cur][(w * 32 + j * 16 + c) * 64 + perm]);
#pragma unroll
            for (int i = 0; i < 4; i++)
#pragma unroll
                for (int j = 0; j < 2; j++)
                    acc[i][j] = __builtin_amdgcn_mfma_f32_16x16x32_bf16(af[i], bfr[j], acc[i][j], 0, 0, 0);
        }
        cur ^= 1;
    }

    // C/D layout: col = lane&15, row = (lane>>4)*4 + reg   [m89/m91]
    if (nt < 8) {
#pragma unroll
        for (int i = 0; i < 4; i++) {
            int row = m0 + i * 16 + q * 4;
#pragma unroll
            for (int j = 0; j < 2; j++) {
                int col = n0 + w * 32 + j * 16 + c;
#pragma unroll
                for (int r = 0; r < 4; r++)
                    xinb[(row + r) * D_MODEL + col] = f2bf(acc[i][j][r]);
            }
        }
    } else if (nt < 16) {
#pragma unroll
        for (int i = 0; i < 4; i++) {
            int row = m0 + i * 16 + q * 4;
#pragma unroll
            for (int j = 0; j < 2; j++) {
                int dcol = n0 + w * 32 + j * 16 + c - D_MODEL;
                float bv = bdt[dcol];
#pragma unroll
                for (int r = 0; r < 4; r++) {
                    float xv = acc[i][j][r] + bv;
                    float sp = fmaxf(xv, 0.f) + __logf(1.f + __expf(-fabsf(xv)));
                    dtb[(row + r) * D_MODEL + dcol] = sp * 0.099f + 0.001f;
                }
            }
        }
    } else if (w == 0) {
#pragma unroll
        for (int i = 0; i < 4; i++) {
            int row = m0 + i * 16 + q * 4;
#pragma unroll
            for (int j = 0; j < 2; j++) {
                int p = j * 16 + c;
#pragma unroll
                for (int r = 0; r < 4; r++)
                    bc[(row + r) * 32 + p] = acc[i][j][r];
            }
        }
    }
}

// ---------- winp[m,n] = B[m,n] * sum_d dt[m,d]*u[m,d]*Aneg[d,n]; 2 rows/block ----------
__global__ void __launch_bounds__(256) k_winp(const float* __restrict__ dt,
                                              const unsigned short* __restrict__ xinb,
                                              const float* __restrict__ aneg,
                                              const float* __restrict__ bc,
                                              float* __restrict__ winp) {
    __shared__ float r0[16][17], r1[16][17];
    int m = blockIdx.x * 2;
    int tid = threadIdx.x;
    int n = tid & 15, strip = tid >> 4;
    float a0 = 0.f, a1 = 0.f;
    int d0 = strip * 64;
    for (int dd = 0; dd < 64; dd++) {
        int d = d0 + dd;
        float g0 = dt[m * D_MODEL + d] * bf2f(xinb[m * D_MODEL + d]);
        float g1 = dt[(m + 1) * D_MODEL + d] * bf2f(xinb[(m + 1) * D_MODEL + d]);
        float av = aneg[d * 16 + n];
        a0 = fmaf(g0, av, a0);
        a1 = fmaf(g1, av, a1);
    }
    r0[strip][n] = a0; r1[strip][n] = a1;
    __syncthreads();
    for (int s = 8; s > 0; s >>= 1) {
        if (strip < s) {
            r0[strip][n] += r0[strip + s][n];
            r1[strip][n] += r1[strip + s][n];
        }
        __syncthreads();
    }
    if (tid < 16) winp[m * 16 + n] = bc[m * 32 + n] * r0[0][n];
    else if (tid < 32) winp[(m + 1) * 16 + n] = bc[(m + 1) * 32 + n] * r1[0][n];
}

// ---------- scan phase 1: chunk-local scan -> h_loc, dtsum ----------
__global__ void __launch_bounds__(256) k_scan1(const float* __restrict__ dt,
                                               const float* __restrict__ winp,
                                               const float* __restrict__ aneg,
                                               float* __restrict__ h_loc,
                                               float* __restrict__ dtsum) {
    __shared__ float s_dt[16][256];
    __shared__ float s_w[16][16];
    int dc = blockIdx.x & 3;
    int c = (blockIdx.x >> 2) & (CHUNKS - 1);
    int b = blockIdx.x >> 8;
    int tid = threadIdx.x;
    int d = dc * 256 + tid;
    float Ad[16];
    const float4* ar = reinterpret_cast<const float4*>(aneg + d * 16);
#pragma unroll
    for (int j = 0; j < 4; j++) {
        float4 a4 = ar[j];
        Ad[4 * j + 0] = a4.x; Ad[4 * j + 1] = a4.y;
        Ad[4 * j + 2] = a4.z; Ad[4 * j + 3] = a4.w;
    }
    float h[16];
#pragma unroll
    for (int n = 0; n < 16; n++) h[n] = 0.f;
    float dts = 0.f;

    for (int t0 = 0; t0 < CLEN; t0 += 16) {
        __syncthreads();
#pragma unroll
        for (int r = 0; r < 16; r++) {
            int row = b * SEQ + c * CLEN + t0 + r;
            s_dt[r][tid] = dt[row * D_MODEL + d];
        }
        {
            int r = tid >> 4, n = tid & 15;
            int row = b * SEQ + c * CLEN + t0 + r;
            s_w[r][n] = winp[row * 16 + n];
        }
        __syncthreads();
        for (int r = 0; r < 16; r++) {
            float dtv = s_dt[r][tid];
            dts += dtv;
#pragma unroll
            for (int n = 0; n < 16; n++) {
                float ba = __expf(dtv * Ad[n]);
                h[n] = fmaf(ba, h[n], s_w[r][n]);
            }
        }
    }
    int base = ((b * CHUNKS + c) * D_MODEL + d) * 16;
#pragma unroll
    for (int j = 0; j < 4; j++) {
        f32x4 v = {h[4 * j], h[4 * j + 1], h[4 * j + 2], h[4 * j + 3]};
        *reinterpret_cast<f32x4*>(h_loc + base + 4 * j) = v;
    }
    dtsum[(b * CHUNKS + c) * D_MODEL + d] = dts;
}

// ---------- scan phase 2: combine chunks (prefetch-pipelined) ----------
__global__ void __launch_bounds__(256) k_scan2(float* __restrict__ h_inout,
                                               const float* __restrict__ dtsum,
                                               const float* __restrict__ aneg) {
    int idx = blockIdx.x * 256 + threadIdx.x;
    int n = idx & 15;
    int d = (idx >> 4) & (D_MODEL - 1);
    int b = idx >> 14;
    float A = aneg[d * 16 + n];
    float H = 0.f;
    int off = (b * CHUNKS) * D_MODEL + d;
    float hl = h_inout[off * 16 + n];
    float ds = dtsum[off];
    for (int c = 0; c < CHUNKS; c++) {
        int off2 = off + D_MODEL;
        float hl_n = 0.f, ds_n = 0.f;
        if (c + 1 < CHUNKS) { hl_n = h_inout[off2 * 16 + n]; ds_n = dtsum[off2]; }
        float P = __expf(ds * A);
        h_inout[off * 16 + n] = H;
        H = fmaf(P, H, hl);
        hl = hl_n; ds = ds_n; off = off2;
    }
}

// ---------- scan phase 3: chunk scan from H_in; emit y ----------
__global__ void __launch_bounds__(256) k_scan3(const float* __restrict__ dt,
                                               const unsigned short* __restrict__ xinb,
                                               const float* __restrict__ winp,
                                               const float* __restrict__ bc,
                                               const float* __restrict__ aneg,
                                               const float* __restrict__ dp,
                                               const float* __restrict__ H_in,
                                               float* __restrict__ out) {
    __shared__ float s_dt[16][256], s_u[16][256], s_w[16][16], s_c[16][16];
    int dc = blockIdx.x & 3;
    int c = (blockIdx.x >> 2) & (CHUNKS - 1);
    int b = blockIdx.x >> 8;
    int tid = threadIdx.x;
    int d = dc * 256 + tid;
    float Ad[16];
    const float4* ar = reinterpret_cast<const float4*>(aneg + d * 16);
#pragma unroll
    for (int j = 0; j < 4; j++) {
        float4 a4 = ar[j];
        Ad[4 * j + 0] = a4.x; Ad[4 * j + 1] = a4.y;
        Ad[4 * j + 2] = a4.z; Ad[4 * j + 3] = a4.w;
    }
    float Dpd = dp[d];
    float h[16];
    int base = ((b * CHUNKS + c) * D_MODEL + d) * 16;
#pragma unroll
    for (int j = 0; j < 4; j++) {
        f32x4 v = *reinterpret_cast<const f32x4*>(H_in + base + 4 * j);
        h[4 * j] = v[0]; h[4 * j + 1] = v[1]; h[4 * j + 2] = v[2]; h[4 * j + 3] = v[3];
    }

    for (int t0 = 0; t0 < CLEN; t0 += 16) {
        __syncthreads();
#pragma unroll
        for (int r = 0; r < 16; r++) {
            int row = b * SEQ + c * CLEN + t0 + r;
            s_dt[r][tid] = dt[row * D_MODEL + d];
            s_u[r][tid] = bf2f(xinb[row * D_MODEL + d]);
        }
        {
            int r = tid >> 4, n = tid & 15;
            int row = b * SEQ + c * CLEN + t0 + r;
            s_w[r][n] = winp[row * 16 + n];
            s_c[r][n] = bc[row * 32 + 16 + n];
        }
        __syncthreads();
        for (int r = 0; r < 16; r++) {
            float dtv = s_dt[r][tid], uv = s_u[r][tid];
            float y = Dpd * uv;
#pragma unroll
            for (int n = 0; n < 16; n++) {
                float ba = __expf(dtv * Ad[n]);
                h[n] = fmaf(ba, h[n], s_w[r][n]);
                y = fmaf(h[n], s_c[r][n], y);
            }
            out[(b * SEQ + c * CLEN + t0 + r) * D_MODEL + d] = y;
        }
    }
}

extern "C" void kernel_launch(void* const* d_in, const int* in_sizes, int n_in,
                              void* d_out, int out_size, void* d_ws, size_t ws_size,
                              hipStream_t stream) {
    const float* x     = (const float*)d_in[0];
    const float* w_in  = (const float*)d_in[1];
    const float* w_x   = (const float*)d_in[2];
    const float* w_dt  = (const float*)d_in[3];
    const float* b_dt  = (const float*)d_in[4];
    const float* A_log = (const float*)d_in[5];
    const float* Dp    = (const float*)d_in[6];
    float* out = (float*)d_out;

    char* ws = (char*)d_ws;
    // footprint capped at 39124992 B (proven safe)
    unsigned short* xb   = (unsigned short*)(ws + 0);          // 8 MB (dead after gemm)
    unsigned short* bt   = (unsigned short*)(ws + 8388608);    // 4.25 MB (dead after gemm)
    float* Tt            = (float*)(ws + 12845056);            // 256 KB
    float* aneg          = (float*)(ws + 13107200);            // 64 KB
    float* bc            = (float*)(ws + 13172736);            // 512 KB
    float* winp          = (float*)(ws + 13697024);            // 256 KB
    unsigned short* xinb = (unsigned short*)(ws + 13959168);   // 8 MB
    float* dtb           = (float*)(ws + 22347776);            // 16 MB -> ends 39124992
    // prep-phase buffers overlay the dtb region (dead until gemm_big writes dtb):
    unsigned short* wib  = (unsigned short*)(ws + 22347776);   // 2 MB   bf16 w_in row-major
    unsigned short* wxT  = (unsigned short*)(ws + 24444928);   // 256 KB bf16 w_x^T (128x1024)
    float* Cp            = (float*)(ws + 24707072);            // 2 MB   K-split partials
    // scan-phase overlays of dead xb/bt regions:
    float* h_loc         = (float*)(ws + 0);                   // 8 MB  [b][c][d][n]
    float* dtsum         = (float*)(ws + 8388608);             // 512 KB [b][c][d]

    k_setup<<<6720, 256, 0, stream>>>(x, w_in, w_x, A_log, xb, wib, bt, wxT, aneg);
    k_prepgemm<<<64, 256, 0, stream>>>(wxT, wib, Cp);
    k_prepreduce<<<768, 256, 0, stream>>>(Cp, Tt, bt);
    k_prep2<<<128, 256, 0, stream>>>(w_dt, Tt, bt);
    k_gemm_big<<<1088, 256, 0, stream>>>(xb, bt, b_dt, xinb, dtb, bc);
    k_winp<<<2048, 256, 0, stream>>>(dtb, xinb, aneg, bc, winp);
    k_scan1<<<BATCH * CHUNKS * 4, 256, 0, stream>>>(dtb, winp, aneg, h_loc, dtsum);
    k_scan2<<<128, 256, 0, stream>>>(h_loc, dtsum, aneg);
    k_scan3<<<BATCH * CHUNKS * 4, 256, 0, stream>>>(dtb, xinb, winp, bc, aneg, Dp, h_loc, out);
}

// Round 8
// 196.450 us; speedup vs baseline: 4.0439x; 1.0130x over previous
//
#include <hip/hip_runtime.h>
#include <hip/hip_bf16.h>

#define D_MODEL 1024
#define D_STATE 16
#define DT_RANK 64
#define SEQ 2048
#define BATCH 2
#define M_TOTAL 4096
#define CHUNKS 64
#define CLEN 32

typedef __bf16 bf16x8 __attribute__((ext_vector_type(8)));
typedef float f32x4 __attribute__((ext_vector_type(4)));

__device__ __forceinline__ unsigned short f2bf(float f) {
    union { float f; unsigned int u; } v; v.f = f;
    unsigned int r = v.u + 0x7FFFu + ((v.u >> 16) & 1u);
    return (unsigned short)(r >> 16);
}
__device__ __forceinline__ float bf2f(unsigned short u) {
    union { unsigned int i; float f; } v; v.i = ((unsigned int)u) << 16; return v.f;
}
__device__ __forceinline__ void gload16(const void* g, void* l) {
    __builtin_amdgcn_global_load_lds(
        (const __attribute__((address_space(1))) unsigned int*)g,
        (__attribute__((address_space(3))) unsigned int*)l, 16, 0, 0);
}

// ---------- fused setup: convert x, convert w_in, transpose w_in, transpose w_x, aneg ----------
__global__ void __launch_bounds__(256) k_setup(const float* __restrict__ x,
                                               const float* __restrict__ win,
                                               const float* __restrict__ wx,
                                               const float* __restrict__ alog,
                                               unsigned short* __restrict__ xb,
                                               unsigned short* __restrict__ wib,
                                               unsigned short* __restrict__ bt,
                                               unsigned short* __restrict__ wxT,
                                               float* __restrict__ aneg) {
    __shared__ float tile[32][33];
    int blk = blockIdx.x;
    int t = threadIdx.x;
    if (blk < 4096) {  // x fp32 -> bf16
        int i = blk * 256 + t;
        float4 v = reinterpret_cast<const float4*>(x)[i];
        ushort4 o;
        o.x = f2bf(v.x); o.y = f2bf(v.y); o.z = f2bf(v.z); o.w = f2bf(v.w);
        reinterpret_cast<ushort4*>(xb)[i] = o;
    } else if (blk < 5120) {  // w_in fp32 -> bf16 row-major
        int i = (blk - 4096) * 256 + t;
        float4 v = reinterpret_cast<const float4*>(win)[i];
        ushort4 o;
        o.x = f2bf(v.x); o.y = f2bf(v.y); o.z = f2bf(v.z); o.w = f2bf(v.w);
        reinterpret_cast<ushort4*>(wib)[i] = o;
    } else if (blk < 6144) {  // w_in^T -> bt rows 0..1023
        int blk2 = blk - 5120;
        int bx = blk2 & 31, by = blk2 >> 5;
        int tx = t & 31, ty = t >> 5;
        int xc = bx * 32 + tx;
#pragma unroll
        for (int j = 0; j < 4; j++)
            tile[ty + 8 * j][tx] = win[(by * 32 + ty + 8 * j) * D_MODEL + xc];
        __syncthreads();
        int x2 = by * 32 + tx;
#pragma unroll
        for (int j = 0; j < 4; j++)
            bt[(bx * 32 + ty + 8 * j) * D_MODEL + x2] = f2bf(tile[tx][ty + 8 * j]);
    } else if (blk < 6656) {  // w_x^T (128x1024, rows 96..127 zero)
        int idx = (blk - 6144) * 256 + t;
        int e = idx & 1023, p = idx >> 10;
        wxT[p * D_MODEL + e] = (p < 96) ? f2bf(wx[e * 96 + p]) : (unsigned short)0;
    } else {  // aneg = -exp(A_log)
        int i = (blk - 6656) * 256 + t;
        if (i < D_MODEL * D_STATE) aneg[i] = -expf(alog[i]);
    }
}

// ---------- prep GEMM: Cp[ks][p][d] partials of (w_x^T @ w_in), 64x128 tile, K=256/block ----------
__global__ void __launch_bounds__(256) k_prepgemm(const unsigned short* __restrict__ wxT,
                                                  const unsigned short* __restrict__ wib,
                                                  float* __restrict__ Cp) {
    __shared__ unsigned short sA[2][64 * 32];
    __shared__ unsigned short sB[2][128 * 32];
    int bid = blockIdx.x;      // 64 = 2 m x 8 n x 4 ksplit
    int m0 = (bid & 1) * 64;
    int n0 = ((bid >> 1) & 7) * 128;
    int ks = bid >> 4;
    int kbase = ks * 256;
    int t = threadIdx.x;
    int lane = t & 63;
    int w = t >> 6;
    int c = lane & 15, q = lane >> 4;

    const unsigned short* ga = wxT + (m0 + (t >> 2)) * D_MODEL + (t & 3) * 8 + kbase;
    const unsigned short* gb = wib + (n0 + (t >> 2)) * D_MODEL + (t & 3) * 8 + kbase;

    f32x4 acc[4][2] = {};
    {
        char* la = (char*)&sA[0][0] + w * 1024;
        char* lb = (char*)&sB[0][0] + w * 1024;
        gload16(ga, la);
        gload16(gb, lb);
        gload16(gb + 64 * D_MODEL, lb + 4096);
    }
    int cur = 0;
    for (int it = 0; it < 8; it++) {
        __syncthreads();
        if (it + 1 < 8) {
            int kn = (it + 1) * 32;
            char* la = (char*)&sA[cur ^ 1][0] + w * 1024;
            char* lb = (char*)&sB[cur ^ 1][0] + w * 1024;
            gload16(ga + kn, la);
            gload16(gb + kn, lb);
            gload16(gb + 64 * D_MODEL + kn, lb + 4096);
        }
        bf16x8 af[4], bfr[2];
#pragma unroll
        for (int i = 0; i < 4; i++)
            af[i] = *reinterpret_cast<const bf16x8*>(&sA[cur][(i * 16 + c) * 32 + q * 8]);
#pragma unroll
        for (int j = 0; j < 2; j++)
            bfr[j] = *reinterpret_cast<const bf16x8*>(&sB[cur][(w * 32 + j * 16 + c) * 32 + q * 8]);
#pragma unroll
        for (int i = 0; i < 4; i++)
#pragma unroll
            for (int j = 0; j < 2; j++)
                acc[i][j] = __builtin_amdgcn_mfma_f32_16x16x32_bf16(af[i], bfr[j], acc[i][j], 0, 0, 0);
        cur ^= 1;
    }
#pragma unroll
    for (int i = 0; i < 4; i++) {
        int p = m0 + i * 16 + q * 4;
#pragma unroll
        for (int j = 0; j < 2; j++) {
            int d = n0 + w * 32 + j * 16 + c;
#pragma unroll
            for (int r = 0; r < 4; r++)
                Cp[(ks * 128 + p + r) * D_MODEL + d] = acc[i][j][r];
        }
    }
}

// ---------- prep reduce: sum K-split partials -> Tt / bt BC rows; zero bt rows 2080.. ----------
__global__ void __launch_bounds__(256) k_prepreduce(const float* __restrict__ Cp,
                                                    float* __restrict__ Tt,
                                                    unsigned short* __restrict__ bt) {
    int idx = blockIdx.x * 256 + threadIdx.x;
    if (idx < 96 * 1024) {
        int d = idx & 1023;
        int p = idx >> 10;
        float s = Cp[p * D_MODEL + d] + Cp[(128 + p) * D_MODEL + d] +
                  Cp[(256 + p) * D_MODEL + d] + Cp[(384 + p) * D_MODEL + d];
        if (p < 64)
            Tt[p * D_MODEL + d] = s;
        else
            bt[(2048 + p - 64) * D_MODEL + d] = f2bf(s);
    } else {
        int j = idx - 96 * 1024;
        bt[(2080 + (j >> 10)) * D_MODEL + (j & 1023)] = 0;
    }
}

// ---------- prep2: bt rows 1024..2047 = (Tt^T @ w_dt)^T bf16 ----------
__global__ void __launch_bounds__(256) k_prep2(const float* __restrict__ wdt,
                                               const float* __restrict__ Tt,
                                               unsigned short* __restrict__ bt) {
    __shared__ float sw[DT_RANK][8];
    int m0 = blockIdx.x * 8;
    int tid = threadIdx.x;
    for (int s = tid; s < DT_RANK * 8; s += 256) {
        int r = s >> 3, rr = s & 7;
        sw[r][rr] = wdt[r * D_MODEL + m0 + rr];
    }
    __syncthreads();
    float acc[8][4] = {};
    for (int r = 0; r < DT_RANK; r++) {
        float tv0 = Tt[r * D_MODEL + tid];
        float tv1 = Tt[r * D_MODEL + tid + 256];
        float tv2 = Tt[r * D_MODEL + tid + 512];
        float tv3 = Tt[r * D_MODEL + tid + 768];
#pragma unroll
        for (int rr = 0; rr < 8; rr++) {
            float wv = sw[r][rr];
            acc[rr][0] = fmaf(wv, tv0, acc[rr][0]);
            acc[rr][1] = fmaf(wv, tv1, acc[rr][1]);
            acc[rr][2] = fmaf(wv, tv2, acc[rr][2]);
            acc[rr][3] = fmaf(wv, tv3, acc[rr][3]);
        }
    }
#pragma unroll
    for (int rr = 0; rr < 8; rr++)
#pragma unroll
        for (int i = 0; i < 4; i++)
            bt[(D_MODEL + m0 + rr) * D_MODEL + tid + i * 256] = f2bf(acc[rr][i]);
}

// ---------- big GEMM: 128x128 tile (m97 shape), BK=64, dbuf, XOR-swizzled LDS ----------
__global__ void __launch_bounds__(256) k_gemm_big(const unsigned short* __restrict__ xb,
                                                  const unsigned short* __restrict__ bt,
                                                  const float* __restrict__ bdt,
                                                  unsigned short* __restrict__ xinb,
                                                  unsigned short* __restrict__ dtb,
                                                  float* __restrict__ bc) {
    __shared__ unsigned short sA[2][128 * 64];  // 16 KB x2
    __shared__ unsigned short sB[2][128 * 64];  // 16 KB x2
    int bid = blockIdx.x;
    int m0 = (bid & 31) * 128;  // M fastest: consecutive blocks share B-slice in L2
    int nt = bid >> 5;          // 0..16
    int n0 = nt * 128;
    int t = threadIdx.x;
    int lane = t & 63;
    int w = t >> 6;
    int wm = (w >> 1) * 64, wn = (w & 1) * 64;
    int c = lane & 15, q = lane >> 4;

    // swizzled staging: slot s (16B): row = s>>3, chunk = (s&7)^(row&7)
    const unsigned short* gA[4];
    const unsigned short* gB[4];
#pragma unroll
    for (int L = 0; L < 4; L++) {
        int s = L * 256 + t;
        int row = s >> 3, ch = (s & 7) ^ (row & 7);
        gA[L] = xb + (m0 + row) * D_MODEL + ch * 8;
        gB[L] = bt + (n0 + row) * D_MODEL + ch * 8;
    }

    f32x4 acc[4][4] = {};
    {
        char* la = (char*)&sA[0][0] + w * 1024;
        char* lb = (char*)&sB[0][0] + w * 1024;
#pragma unroll
        for (int L = 0; L < 4; L++) {
            gload16(gA[L], la + L * 4096);
            gload16(gB[L], lb + L * 4096);
        }
    }
    int cur = 0;
    for (int it = 0; it < 16; it++) {
        __syncthreads();
        if (it + 1 < 16) {
            int kn = (it + 1) * 64;
            char* la = (char*)&sA[cur ^ 1][0] + w * 1024;
            char* lb = (char*)&sB[cur ^ 1][0] + w * 1024;
#pragma unroll
            for (int L = 0; L < 4; L++) {
                gload16(gA[L] + kn, la + L * 4096);
                gload16(gB[L] + kn, lb + L * 4096);
            }
        }
#pragma unroll
        for (int kk = 0; kk < 2; kk++) {
            int perm = (((kk << 2) | q) ^ (c & 7)) << 3;
            bf16x8 af[4], bfr[4];
#pragma unroll
            for (int i = 0; i < 4; i++)
                af[i] = *reinterpret_cast<const bf16x8*>(&sA[cur][(wm + i * 16 + c) * 64 + perm]);
#pragma unroll
            for (int j = 0; j < 4; j++)
                bfr[j] = *reinterpret_cast<const bf16x8*>(&sB[cur][(wn + j * 16 + c) * 64 + perm]);
#pragma unroll
            for (int i = 0; i < 4; i++)
#pragma unroll
                for (int j = 0; j < 4; j++)
                    acc[i][j] = __builtin_amdgcn_mfma_f32_16x16x32_bf16(af[i], bfr[j], acc[i][j], 0, 0, 0);
        }
        cur ^= 1;
    }

    // C/D layout: col = lane&15, row = (lane>>4)*4 + reg   [m89/m91]
    if (nt < 8) {
#pragma unroll
        for (int i = 0; i < 4; i++) {
            int row = m0 + wm + i * 16 + q * 4;
#pragma unroll
            for (int j = 0; j < 4; j++) {
                int col = n0 + wn + j * 16 + c;
#pragma unroll
                for (int r = 0; r < 4; r++)
                    xinb[(row + r) * D_MODEL + col] = f2bf(acc[i][j][r]);
            }
        }
    } else if (nt < 16) {
#pragma unroll
        for (int i = 0; i < 4; i++) {
            int row = m0 + wm + i * 16 + q * 4;
#pragma unroll
            for (int j = 0; j < 4; j++) {
                int dcol = n0 + wn + j * 16 + c - D_MODEL;
                float bv = bdt[dcol];
#pragma unroll
                for (int r = 0; r < 4; r++) {
                    float xv = acc[i][j][r] + bv;
                    float sp = fmaxf(xv, 0.f) + __logf(1.f + __expf(-fabsf(xv)));
                    dtb[(row + r) * D_MODEL + dcol] = f2bf(sp * 0.099f + 0.001f);
                }
            }
        }
    } else if (wn == 0) {  // BC tile: cols 2048..2079 (j<2)
#pragma unroll
        for (int i = 0; i < 4; i++) {
            int row = m0 + wm + i * 16 + q * 4;
#pragma unroll
            for (int j = 0; j < 2; j++) {
                int p = j * 16 + c;
#pragma unroll
                for (int r = 0; r < 4; r++)
                    bc[(row + r) * 32 + p] = acc[i][j][r];
            }
        }
    }
}

// ---------- winp[m,n] = B[m,n] * sum_d dt[m,d]*u[m,d]*Aneg[d,n]; vectorized ----------
__global__ void __launch_bounds__(256) k_winp(const unsigned short* __restrict__ dtb,
                                              const unsigned short* __restrict__ xinb,
                                              const float* __restrict__ aneg,
                                              const float* __restrict__ bc,
                                              float* __restrict__ winp) {
    __shared__ float r0[16][17], r1[16][17];
    int m = blockIdx.x * 2;
    int tid = threadIdx.x;
    int n = tid & 15, strip = tid >> 4;
    float a0 = 0.f, a1 = 0.f;
    int d0 = strip * 64;
    for (int dd = 0; dd < 64; dd += 4) {
        int d = d0 + dd;
        ushort4 t0 = *reinterpret_cast<const ushort4*>(dtb + m * D_MODEL + d);
        ushort4 u0 = *reinterpret_cast<const ushort4*>(xinb + m * D_MODEL + d);
        ushort4 t1 = *reinterpret_cast<const ushort4*>(dtb + (m + 1) * D_MODEL + d);
        ushort4 u1 = *reinterpret_cast<const ushort4*>(xinb + (m + 1) * D_MODEL + d);
        float av0 = aneg[(d + 0) * 16 + n];
        float av1 = aneg[(d + 1) * 16 + n];
        float av2 = aneg[(d + 2) * 16 + n];
        float av3 = aneg[(d + 3) * 16 + n];
        a0 = fmaf(bf2f(t0.x) * bf2f(u0.x), av0, a0);
        a0 = fmaf(bf2f(t0.y) * bf2f(u0.y), av1, a0);
        a0 = fmaf(bf2f(t0.z) * bf2f(u0.z), av2, a0);
        a0 = fmaf(bf2f(t0.w) * bf2f(u0.w), av3, a0);
        a1 = fmaf(bf2f(t1.x) * bf2f(u1.x), av0, a1);
        a1 = fmaf(bf2f(t1.y) * bf2f(u1.y), av1, a1);
        a1 = fmaf(bf2f(t1.z) * bf2f(u1.z), av2, a1);
        a1 = fmaf(bf2f(t1.w) * bf2f(u1.w), av3, a1);
    }
    r0[strip][n] = a0; r1[strip][n] = a1;
    __syncthreads();
    for (int s = 8; s > 0; s >>= 1) {
        if (strip < s) {
            r0[strip][n] += r0[strip + s][n];
            r1[strip][n] += r1[strip + s][n];
        }
        __syncthreads();
    }
    if (tid < 16) winp[m * 16 + n] = bc[m * 32 + n] * r0[0][n];
    else if (tid < 32) winp[(m + 1) * 16 + n] = bc[(m + 1) * 32 + n] * r1[0][n];
}

// ---------- scan phase 1: chunk-local scan -> h_loc, dtsum ----------
__global__ void __launch_bounds__(256) k_scan1(const unsigned short* __restrict__ dtb,
                                               const float* __restrict__ winp,
                                               const float* __restrict__ aneg,
                                               float* __restrict__ h_loc,
                                               float* __restrict__ dtsum) {
    __shared__ float s_dt[16][256];
    __shared__ float s_w[16][16];
    int dc = blockIdx.x & 3;
    int c = (blockIdx.x >> 2) & (CHUNKS - 1);
    int b = blockIdx.x >> 8;
    int tid = threadIdx.x;
    int d = dc * 256 + tid;
    float Ad[16];
    const float4* ar = reinterpret_cast<const float4*>(aneg + d * 16);
#pragma unroll
    for (int j = 0; j < 4; j++) {
        float4 a4 = ar[j];
        Ad[4 * j + 0] = a4.x; Ad[4 * j + 1] = a4.y;
        Ad[4 * j + 2] = a4.z; Ad[4 * j + 3] = a4.w;
    }
    float h[16];
#pragma unroll
    for (int n = 0; n < 16; n++) h[n] = 0.f;
    float dts = 0.f;

    for (int t0 = 0; t0 < CLEN; t0 += 16) {
        __syncthreads();
#pragma unroll
        for (int r = 0; r < 16; r++) {
            int row = b * SEQ + c * CLEN + t0 + r;
            s_dt[r][tid] = bf2f(dtb[row * D_MODEL + d]);
        }
        {
            int r = tid >> 4, n = tid & 15;
            int row = b * SEQ + c * CLEN + t0 + r;
            s_w[r][n] = winp[row * 16 + n];
        }
        __syncthreads();
        for (int r = 0; r < 16; r++) {
            float dtv = s_dt[r][tid];
            dts += dtv;
#pragma unroll
            for (int n = 0; n < 16; n++) {
                float ba = __expf(dtv * Ad[n]);
                h[n] = fmaf(ba, h[n], s_w[r][n]);
            }
        }
    }
    int base = ((b * CHUNKS + c) * D_MODEL + d) * 16;
#pragma unroll
    for (int j = 0; j < 4; j++) {
        f32x4 v = {h[4 * j], h[4 * j + 1], h[4 * j + 2], h[4 * j + 3]};
        *reinterpret_cast<f32x4*>(h_loc + base + 4 * j) = v;
    }
    dtsum[(b * CHUNKS + c) * D_MODEL + d] = dts;
}

// ---------- scan phase 2: combine chunks (prefetch-pipelined) ----------
__global__ void __launch_bounds__(256) k_scan2(float* __restrict__ h_inout,
                                               const float* __restrict__ dtsum,
                                               const float* __restrict__ aneg) {
    int idx = blockIdx.x * 256 + threadIdx.x;
    int n = idx & 15;
    int d = (idx >> 4) & (D_MODEL - 1);
    int b = idx >> 14;
    float A = aneg[d * 16 + n];
    float H = 0.f;
    int off = (b * CHUNKS) * D_MODEL + d;
    float hl = h_inout[off * 16 + n];
    float ds = dtsum[off];
    for (int c = 0; c < CHUNKS; c++) {
        int off2 = off + D_MODEL;
        float hl_n = 0.f, ds_n = 0.f;
        if (c + 1 < CHUNKS) { hl_n = h_inout[off2 * 16 + n]; ds_n = dtsum[off2]; }
        float P = __expf(ds * A);
        h_inout[off * 16 + n] = H;
        H = fmaf(P, H, hl);
        hl = hl_n; ds = ds_n; off = off2;
    }
}

// ---------- scan phase 3: chunk scan from H_in; emit y ----------
__global__ void __launch_bounds__(256) k_scan3(const unsigned short* __restrict__ dtb,
                                               const unsigned short* __restrict__ xinb,
                                               const float* __restrict__ winp,
                                               const float* __restrict__ bc,
                                               const float* __restrict__ aneg,
                                               const float* __restrict__ dp,
                                               const float* __restrict__ H_in,
                                               float* __restrict__ out) {
    __shared__ float s_dt[16][256], s_u[16][256], s_w[16][16], s_c[16][16];
    int dc = blockIdx.x & 3;
    int c = (blockIdx.x >> 2) & (CHUNKS - 1);
    int b = blockIdx.x >> 8;
    int tid = threadIdx.x;
    int d = dc * 256 + tid;
    float Ad[16];
    const float4* ar = reinterpret_cast<const float4*>(aneg + d * 16);
#pragma unroll
    for (int j = 0; j < 4; j++) {
        float4 a4 = ar[j];
        Ad[4 * j + 0] = a4.x; Ad[4 * j + 1] = a4.y;
        Ad[4 * j + 2] = a4.z; Ad[4 * j + 3] = a4.w;
    }
    float Dpd = dp[d];
    float h[16];
    int base = ((b * CHUNKS + c) * D_MODEL + d) * 16;
#pragma unroll
    for (int j = 0; j < 4; j++) {
        f32x4 v = *reinterpret_cast<const f32x4*>(H_in + base + 4 * j);
        h[4 * j] = v[0]; h[4 * j + 1] = v[1]; h[4 * j + 2] = v[2]; h[4 * j + 3] = v[3];
    }

    for (int t0 = 0; t0 < CLEN; t0 += 16) {
        __syncthreads();
#pragma unroll
        for (int r = 0; r < 16; r++) {
            int row = b * SEQ + c * CLEN + t0 + r;
            s_dt[r][tid] = bf2f(dtb[row * D_MODEL + d]);
            s_u[r][tid] = bf2f(xinb[row * D_MODEL + d]);
        }
        {
            int r = tid >> 4, n = tid & 15;
            int row = b * SEQ + c * CLEN + t0 + r;
            s_w[r][n] = winp[row * 16 + n];
            s_c[r][n] = bc[row * 32 + 16 + n];
        }
        __syncthreads();
        for (int r = 0; r < 16; r++) {
            float dtv = s_dt[r][tid], uv = s_u[r][tid];
            float y = Dpd * uv;
#pragma unroll
            for (int n = 0; n < 16; n++) {
                float ba = __expf(dtv * Ad[n]);
                h[n] = fmaf(ba, h[n], s_w[r][n]);
                y = fmaf(h[n], s_c[r][n], y);
            }
            out[(b * SEQ + c * CLEN + t0 + r) * D_MODEL + d] = y;
        }
    }
}

extern "C" void kernel_launch(void* const* d_in, const int* in_sizes, int n_in,
                              void* d_out, int out_size, void* d_ws, size_t ws_size,
                              hipStream_t stream) {
    const float* x     = (const float*)d_in[0];
    const float* w_in  = (const float*)d_in[1];
    const float* w_x   = (const float*)d_in[2];
    const float* w_dt  = (const float*)d_in[3];
    const float* b_dt  = (const float*)d_in[4];
    const float* A_log = (const float*)d_in[5];
    const float* Dp    = (const float*)d_in[6];
    float* out = (float*)d_out;

    char* ws = (char*)d_ws;
    // footprint capped below proven-safe 39124992 B
    unsigned short* xb   = (unsigned short*)(ws + 0);          // 8 MB (dead after gemm)
    unsigned short* bt   = (unsigned short*)(ws + 8388608);    // 4.25 MB (dead after gemm)
    float* Tt            = (float*)(ws + 12845056);            // 256 KB
    float* aneg          = (float*)(ws + 13107200);            // 64 KB
    float* bc            = (float*)(ws + 13172736);            // 512 KB
    float* winp          = (float*)(ws + 13697024);            // 256 KB
    unsigned short* xinb = (unsigned short*)(ws + 13959168);   // 8 MB
    unsigned short* dtb  = (unsigned short*)(ws + 22347776);   // 8 MB bf16 -> ends 30736384
    // prep-phase buffers overlay the dtb region (dead until gemm_big writes dtb):
    unsigned short* wib  = (unsigned short*)(ws + 22347776);   // 2 MB   bf16 w_in row-major
    unsigned short* wxT  = (unsigned short*)(ws + 24444928);   // 256 KB bf16 w_x^T (128x1024)
    float* Cp            = (float*)(ws + 24707072);            // 2 MB   K-split partials
    // scan-phase overlays of dead xb/bt regions:
    float* h_loc         = (float*)(ws + 0);                   // 8 MB  [b][c][d][n]
    float* dtsum         = (float*)(ws + 8388608);             // 512 KB [b][c][d]

    k_setup<<<6720, 256, 0, stream>>>(x, w_in, w_x, A_log, xb, wib, bt, wxT, aneg);
    k_prepgemm<<<64, 256, 0, stream>>>(wxT, wib, Cp);
    k_prepreduce<<<768, 256, 0, stream>>>(Cp, Tt, bt);
    k_prep2<<<128, 256, 0, stream>>>(w_dt, Tt, bt);
    k_gemm_big<<<544, 256, 0, stream>>>(xb, bt, b_dt, xinb, dtb, bc);
    k_winp<<<2048, 256, 0, stream>>>(dtb, xinb, aneg, bc, winp);
    k_scan1<<<BATCH * CHUNKS * 4, 256, 0, stream>>>(dtb, winp, aneg, h_loc, dtsum);
    k_scan2<<<128, 256, 0, stream>>>(h_loc, dtsum, aneg);
    k_scan3<<<BATCH * CHUNKS * 4, 256, 0, stream>>>(dtb, xinb, winp, bc, aneg, Dp, h_loc, out);
}